// Round 4
// baseline (407.303 us; speedup 1.0000x reference)
//
#include <hip/hip_runtime.h>
#include <stdint.h>

using f32x4  = __attribute__((ext_vector_type(4))) float;
using short8 = __attribute__((ext_vector_type(8))) short;
typedef unsigned short u16;
typedef unsigned int   u32;

// B=8, H=8, L=1024, DM=512, DK=DV=64.  M = B*L = 8192.

static __device__ __forceinline__ u16 f2bf(float f) {
  union { float f; u32 u; } v; v.f = f;
  u32 r = v.u + 0x7fffu + ((v.u >> 16) & 1u);   // RNE
  return (u16)(r >> 16);
}
static __device__ __forceinline__ float bf2f(u16 u) {
  union { u32 u; float f; } v; v.u = ((u32)u) << 16;
  return v.f;
}

// async global->LDS, 16B per lane; LDS dest = wave-uniform base + lane*16
#define GLDS16(g, l) __builtin_amdgcn_global_load_lds( \
    (const __attribute__((address_space(1))) u32*)(g), \
    (__attribute__((address_space(3))) u32*)(l), 16, 0, 0)

// ------- 4 weight transposes in one launch: W [512k][512n] -> Wt [n][k] bf16
__global__ __launch_bounds__(256) void k_wt4(const float* __restrict__ W0, const float* __restrict__ W1,
                                             const float* __restrict__ W2, const float* __restrict__ W3,
                                             u16* __restrict__ T0, u16* __restrict__ T1,
                                             u16* __restrict__ T2, u16* __restrict__ T3) {
  const float* W = (blockIdx.z == 0) ? W0 : (blockIdx.z == 1) ? W1 : (blockIdx.z == 2) ? W2 : W3;
  u16* T = (blockIdx.z == 0) ? T0 : (blockIdx.z == 1) ? T1 : (blockIdx.z == 2) ? T2 : T3;
  __shared__ float t[32][33];
  int tx = threadIdx.x & 31, ty = threadIdx.x >> 5;   // 32 x 8
  int x0 = blockIdx.x * 32, y0 = blockIdx.y * 32;     // x = n, y = k
  #pragma unroll
  for (int i = 0; i < 4; i++)
    t[ty + i*8][tx] = W[(y0 + ty + i*8) * 512 + (x0 + tx)];
  __syncthreads();
  #pragma unroll
  for (int i = 0; i < 4; i++)
    T[(x0 + ty + i*8) * 512 + (y0 + tx)] = f2bf(t[tx][ty + i*8]);
}

// ------------- rel embeddings: relk80 [80][64] (zero-pad rows>=65),
//               relvT [64 dv][96 bucket] (zero-pad buckets>=65) -------------
__global__ __launch_bounds__(256) void k_prep_rel(const float* __restrict__ rk,
                                                  const float* __restrict__ rv,
                                                  u16* __restrict__ relk80,
                                                  u16* __restrict__ relvT) {
  int i = blockIdx.x * 256 + threadIdx.x;
  if (i < 80*64) {
    int row = i >> 6;
    relk80[i] = (row < 65) ? f2bf(rk[i]) : (u16)0;
  }
  int j = i - 80*64;
  if (j >= 0 && j < 64*96) {
    int dv = j / 96, bk = j % 96;
    relvT[j] = (bk < 65) ? f2bf(rv[bk*64 + dv]) : (u16)0;
  }
}

// ------------- fp32 -> bf16 for query/key/value in one launch -------------
__global__ __launch_bounds__(256) void k_cvt3(const float* __restrict__ a, const float* __restrict__ b,
                                              const float* __restrict__ c,
                                              u16* __restrict__ oa, u16* __restrict__ ob,
                                              u16* __restrict__ oc) {
  const float* src = (blockIdx.y == 0) ? a : (blockIdx.y == 1) ? b : c;
  u16* dst = (blockIdx.y == 0) ? oa : (blockIdx.y == 1) ? ob : oc;
  int i = blockIdx.x * 256 + threadIdx.x;
  float4 v = ((const float4*)src)[i];
  ushort4 o;
  o.x = f2bf(v.x); o.y = f2bf(v.y); o.z = f2bf(v.z); o.w = f2bf(v.w);
  ((ushort4*)dst)[i] = o;
}

// ------------- pack rel_matrix | mask<<7 | bf16(rel_mask)<<16 -> u32 -------
__global__ __launch_bounds__(256) void k_pack(const int* __restrict__ rm,
                                              const float* __restrict__ rw,
                                              const unsigned char* __restrict__ mk,
                                              u32* __restrict__ outp) {
  int i = blockIdx.x * 256 + threadIdx.x;     // x4 elements
  int4   r4 = ((const int4*)rm)[i];
  float4 w4 = ((const float4*)rw)[i];
  uchar4 m4 = ((const uchar4*)mk)[i];
  uint4 o;
  o.x = (u32)(r4.x & 63) | (m4.x ? 128u : 0u) | ((u32)f2bf(w4.x) << 16);
  o.y = (u32)(r4.y & 63) | (m4.y ? 128u : 0u) | ((u32)f2bf(w4.y) << 16);
  o.z = (u32)(r4.z & 63) | (m4.z ? 128u : 0u) | ((u32)f2bf(w4.z) << 16);
  o.w = (u32)(r4.w & 63) | (m4.w ? 128u : 0u) | ((u32)f2bf(w4.w) << 16);
  ((uint4*)outp)[i] = o;
}

// ---------------- bf16 MFMA GEMM: C = A[8192,512] @ Wt^T + bias -----------
struct GArg { const u16* A; const u16* Wt; const float* bias; void* out; int mode; float scale; };

__global__ __launch_bounds__(256) void k_gemm(GArg g0, GArg g1, GArg g2) {
  GArg ar = (blockIdx.z == 0) ? g0 : (blockIdx.z == 1) ? g1 : g2;
  __shared__ u16 As[128*32];   // chunk c (16B) at byte c*16: row=c>>2, slot=c&3
  __shared__ u16 Bs[64*32];
  __shared__ u16 Cs[9216];     // mode1: [128][72] pad; mode2 (transposed): [64][136] pad
  int tid = threadIdx.x, lane = tid & 63, wv = tid >> 6;
  int quad = lane >> 4, l15 = lane & 15;
  int n0 = blockIdx.x * 64, m0 = blockIdx.y * 128;
  int wm = (wv >> 1) * 64, wn = (wv & 1) * 32;
  f32x4 acc[4][2];
  #pragma unroll
  for (int i = 0; i < 4; i++)
    #pragma unroll
    for (int j = 0; j < 2; j++)
      acc[i][j] = (f32x4){0.f, 0.f, 0.f, 0.f};

  const u16* Abase = ar.A  + (size_t)m0 * 512;
  const u16* Bbase = ar.Wt + (size_t)n0 * 512;
  int cA0 = wv * 128, cB0 = wv * 64;      // wave-uniform chunk bases

  for (int k0 = 0; k0 < 512; k0 += 32) {
    #pragma unroll
    for (int i = 0; i < 2; i++) {
      int c = cA0 + i*64 + lane;
      GLDS16(Abase + (c >> 2)*512 + k0 + (c & 3)*8, &As[(cA0 + i*64)*8]);
    }
    {
      int c = cB0 + lane;
      GLDS16(Bbase + (c >> 2)*512 + k0 + (c & 3)*8, &Bs[cB0*8]);
    }
    __syncthreads();
    short8 af[4], bf[2];
    #pragma unroll
    for (int i = 0; i < 4; i++) af[i] = *(const short8*)&As[(wm + i*16 + l15)*32 + quad*8];
    #pragma unroll
    for (int j = 0; j < 2; j++) bf[j] = *(const short8*)&Bs[(wn + j*16 + l15)*32 + quad*8];
    #pragma unroll
    for (int i = 0; i < 4; i++)
      #pragma unroll
      for (int j = 0; j < 2; j++)
        acc[i][j] = __builtin_amdgcn_mfma_f32_16x16x32_bf16(af[i], bf[j], acc[i][j], 0, 0, 0);
    __syncthreads();
  }

  if (ar.mode == 0) {
    #pragma unroll
    for (int i = 0; i < 4; i++)
      #pragma unroll
      for (int j = 0; j < 2; j++) {
        int ncol = n0 + wn + j*16 + l15;
        float bv = ar.bias[ncol];
        #pragma unroll
        for (int r = 0; r < 4; r++) {
          int m = m0 + wm + i*16 + quad*4 + r;
          ((float*)ar.out)[m*512 + ncol] = (acc[i][j][r] + bv) * ar.scale;
        }
      }
  } else {
    #pragma unroll
    for (int i = 0; i < 4; i++)
      #pragma unroll
      for (int j = 0; j < 2; j++) {
        int nloc = wn + j*16 + l15;
        float bv = ar.bias[n0 + nloc];
        #pragma unroll
        for (int r = 0; r < 4; r++) {
          int mloc = wm + i*16 + quad*4 + r;
          float val = (acc[i][j][r] + bv) * ar.scale;
          if (ar.mode == 1) Cs[mloc*72 + nloc] = f2bf(val);
          else              Cs[nloc*136 + mloc] = f2bf(val);
        }
      }
    __syncthreads();
    int bb = m0 >> 10, hh = n0 >> 6, mbase = m0 & 1023;
    u16* outp = (u16*)ar.out;
    if (ar.mode == 1) {
      size_t base = ((size_t)(bb*8 + hh)*1024 + mbase)*64;
      #pragma unroll
      for (int p = 0; p < 4; p++) {
        int mloc = (tid >> 3) + p*32, seg = tid & 7;
        *(short8*)(outp + base + (size_t)mloc*64 + seg*8) = *(const short8*)&Cs[mloc*72 + seg*8];
      }
    } else {
      size_t base = (size_t)(bb*8 + hh)*64*1024 + mbase;
      #pragma unroll
      for (int p = 0; p < 4; p++) {
        int d = (tid >> 4) + p*16, seg = tid & 15;
        *(short8*)(outp + base + (size_t)d*1024 + seg*8) = *(const short8*)&Cs[d*136 + seg*8];
      }
    }
  }
}

// ---------------- fused attention, split-K ----------------
// R9: wave-supply was the cap (4096 waves = 16/CU max; all pipes <35%,
// R8 in-wave pipelining null). blockIdx.z in {0,1} splits the 32 k-tiles
// per (b,qt,head-group): ks0 -> [0,mid), ks1 -> [mid,32), mid chosen per qt
// so the diagonal band lives entirely in one half. 8192 waves now.
// Blocks write partial O (f32) + (ts0,ts1,rs_band) per q-row; k_comb adds
// halves + the LINEAR far-mass relv correction ts0*relv[0]+ts1*relv[64]
// (those GEMM rows are separable), divides, emits bf16 ctx.
// All LDS (qdotL/PB/Pl) is per-wave -> PB zeroed per-wave -> NO barriers.
__global__ __launch_bounds__(256, 3) void k_attn(
    const u16* __restrict__ qws, const u16* __restrict__ kws, const u16* __restrict__ vtws,
    const u16* __restrict__ relk80, const u16* __restrict__ relvT,
    const float* __restrict__ tree_emb, const u32* __restrict__ packed,
    float* __restrict__ opart, float* __restrict__ spart) {
  __shared__ u16 qdotL[4*16*68];    // [w][q][bucket]  (band blocks only)
  __shared__ u16 PB[4][16*96];      // per-wave banded P
  __shared__ u16 Pl[4][16*40];      // per-wave C->A bridge, stride 40

  int tid = threadIdx.x, lane = tid & 63, wv = tid >> 6;
  int quad = lane >> 4, l15 = lane & 15;
  int b = blockIdx.x & 7, qt = blockIdx.x >> 3;
  int hg = blockIdx.y;
  int ks = blockIdx.z;
  int q0 = qt * 16;
  int h = hg * 4 + wv;

  // band tile range and k-split point (band kept whole in one half)
  int t_lo = max(0, (q0 - 31) >> 5);
  int t_hi = min(31, (q0 + 46) >> 5);
  int mid = (t_lo < 16 && t_hi >= 16) ? t_lo : 16;
  int lo = ks ? mid : 0;
  int hi = ks ? 32 : mid;
  bool hasBand = (t_lo >= lo && t_lo < hi);

  // register tree table: lane v (0..63) holds tree_emb[v][h] * log2e
  float treev = tree_emb[lane * 8 + h] * 1.44269504f;

  if (hasBand) {
    #pragma unroll
    for (int i = 0; i < 12; i++) ((u32*)&PB[wv][0])[lane + i*64] = 0u;
  }

  const u16* qb = qws  + (size_t)(b*8 + h)*(1024*64);
  const u16* kb = kws  + (size_t)(b*8 + h)*(1024*64);
  const u16* vb = vtws + (size_t)(b*8 + h)*(64*1024);
  const u32* pkb = packed + ((size_t)b << 20);

  short8 aQ[2];
  #pragma unroll
  for (int kf = 0; kf < 2; kf++)
    aQ[kf] = *(const short8*)(qb + (q0 + l15)*64 + kf*32 + quad*8);

  float qd0[4], qd64[4];
  if (hasBand) {
    #pragma unroll
    for (int t = 0; t < 5; t++) {
      f32x4 C = (f32x4){0.f,0.f,0.f,0.f};
      #pragma unroll
      for (int kf = 0; kf < 2; kf++) {
        short8 bR = *(const short8*)(relk80 + (t*16 + l15)*64 + kf*32 + quad*8);
        C = __builtin_amdgcn_mfma_f32_16x16x32_bf16(aQ[kf], bR, C, 0, 0, 0);
      }
      if (t == 0) {
        #pragma unroll
        for (int r = 0; r < 4; r++) qd0[r] = __shfl(C[r], lane & 48, 64);
      }
      if (t == 4) {
        #pragma unroll
        for (int r = 0; r < 4; r++) qd64[r] = __shfl(C[r], lane & 48, 64);
      }
      int col = t*16 + l15;
      if (col < 65) {
        #pragma unroll
        for (int r = 0; r < 4; r++)
          qdotL[(wv*16 + quad*4 + r)*68 + col] = f2bf(C[r]);
      }
    }
  } else {
    #pragma unroll
    for (int tt = 0; tt < 2; tt++) {
      int t = tt ? 4 : 0;
      f32x4 C = (f32x4){0.f,0.f,0.f,0.f};
      #pragma unroll
      for (int kf = 0; kf < 2; kf++) {
        short8 bR = *(const short8*)(relk80 + (t*16 + l15)*64 + kf*32 + quad*8);
        C = __builtin_amdgcn_mfma_f32_16x16x32_bf16(aQ[kf], bR, C, 0, 0, 0);
      }
      if (tt == 0) {
        #pragma unroll
        for (int r = 0; r < 4; r++) qd0[r] = __shfl(C[r], lane & 48, 64);
      } else {
        #pragma unroll
        for (int r = 0; r < 4; r++) qd64[r] = __shfl(C[r], lane & 48, 64);
      }
    }
  }

  // ---- pipeline prologue: S for tile lo; prefetch K(lo+1), sg(lo->pkc, lo+1->pk)
  short8 kreg[2][2];
  #pragma unroll
  for (int ct = 0; ct < 2; ct++)
    #pragma unroll
    for (int kf = 0; kf < 2; kf++)
      kreg[ct][kf] = *(const short8*)(kb + ((lo<<5) + ct*16 + l15)*64 + kf*32 + quad*8);
  u32 pk[8];
  #pragma unroll
  for (int e = 0; e < 8; e++) {
    int ct = e >> 2, r = e & 3;
    pk[e] = pkb[((q0 + quad*4 + r) << 10) + (lo<<5) + ct*16 + l15];
  }

  f32x4 Scur[2];
  #pragma unroll
  for (int ct = 0; ct < 2; ct++) {
    f32x4 c = (f32x4){0.f,0.f,0.f,0.f};
    #pragma unroll
    for (int kf = 0; kf < 2; kf++)
      c = __builtin_amdgcn_mfma_f32_16x16x32_bf16(aQ[kf], kreg[ct][kf], c, 0, 0, 0);
    Scur[ct] = c;
  }
  #pragma unroll
  for (int ct = 0; ct < 2; ct++)
    #pragma unroll
    for (int kf = 0; kf < 2; kf++)
      kreg[ct][kf] = *(const short8*)(kb + (((lo+1)<<5) + ct*16 + l15)*64 + kf*32 + quad*8);
  u32 pkc[8];
  #pragma unroll
  for (int e = 0; e < 8; e++) pkc[e] = pk[e];
  #pragma unroll
  for (int e = 0; e < 8; e++) {
    int ct = e >> 2, r = e & 3;
    pk[e] = pkb[((q0 + quad*4 + r) << 10) + ((lo+1)<<5) + ct*16 + l15];
  }

  f32x4 O[4];
  float rs[4], ts0[4], ts1[4];
  #pragma unroll
  for (int t = 0; t < 4; t++) O[t] = (f32x4){0.f,0.f,0.f,0.f};
  #pragma unroll
  for (int r = 0; r < 4; r++) { rs[r] = 0.f; ts0[r] = 0.f; ts1[r] = 0.f; }

  for (int jt = lo; jt < hi; ++jt) {
    int k0 = jt << 5;
    short8 vreg[4];
    #pragma unroll
    for (int t = 0; t < 4; t++)
      vreg[t] = *(const short8*)(vb + (t*16 + l15)*1024 + k0 + quad*8);

    // S for NEXT tile (kreg prefetched last iter); then K prefetch jt+2
    f32x4 Sn0, Sn1;
    if (jt < hi - 1) {
      __builtin_amdgcn_s_setprio(1);
      {
        f32x4 c = (f32x4){0.f,0.f,0.f,0.f};
        #pragma unroll
        for (int kf = 0; kf < 2; kf++)
          c = __builtin_amdgcn_mfma_f32_16x16x32_bf16(aQ[kf], kreg[0][kf], c, 0, 0, 0);
        Sn0 = c;
        c = (f32x4){0.f,0.f,0.f,0.f};
        #pragma unroll
        for (int kf = 0; kf < 2; kf++)
          c = __builtin_amdgcn_mfma_f32_16x16x32_bf16(aQ[kf], kreg[1][kf], c, 0, 0, 0);
        Sn1 = c;
      }
      __builtin_amdgcn_s_setprio(0);
      int k2 = (jt + 2 < hi) ? ((jt + 2) << 5) : (lo << 5);
      #pragma unroll
      for (int ct = 0; ct < 2; ct++)
        #pragma unroll
        for (int kf = 0; kf < 2; kf++)
          kreg[ct][kf] = *(const short8*)(kb + (k2 + ct*16 + l15)*64 + kf*32 + quad*8);
    }

    // ---- softmax for tile jt (Scur, pkc) under the matrix pipe
    if (jt < t_lo) {
      #pragma unroll
      for (int ct = 0; ct < 2; ct++) {
        #pragma unroll
        for (int r = 0; r < 4; r++) {
          u32 sg = pkc[ct*4 + r];
          float rw = __uint_as_float(sg & 0xffff0000u);
          float tb = __int_as_float(__builtin_amdgcn_ds_bpermute(
              (int)((sg & 63u) << 2), __float_as_int(treev)));
          float qm = (sg & 128u) ? -1e30f : qd0[r];
          float p = exp2f(__builtin_fmaf(tb, rw, Scur[ct][r] + qm));
          ts0[r] += p;
          Pl[wv][(quad*4 + r)*40 + ct*16 + l15] = f2bf(p);
        }
      }
    } else if (jt > t_hi) {
      #pragma unroll
      for (int ct = 0; ct < 2; ct++) {
        #pragma unroll
        for (int r = 0; r < 4; r++) {
          u32 sg = pkc[ct*4 + r];
          float rw = __uint_as_float(sg & 0xffff0000u);
          float tb = __int_as_float(__builtin_amdgcn_ds_bpermute(
              (int)((sg & 63u) << 2), __float_as_int(treev)));
          float qm = (sg & 128u) ? -1e30f : qd64[r];
          float p = exp2f(__builtin_fmaf(tb, rw, Scur[ct][r] + qm));
          ts1[r] += p;
          Pl[wv][(quad*4 + r)*40 + ct*16 + l15] = f2bf(p);
        }
      }
    } else {
      #pragma unroll
      for (int ct = 0; ct < 2; ct++) {
        #pragma unroll
        for (int r = 0; r < 4; r++) {
          int kloc = ct*16 + l15, qloc = quad*4 + r;
          int d = (k0 + kloc) - (q0 + qloc);
          int bucket = min(max(d + 32, 0), 64);
          u32 sg = pkc[ct*4 + r];
          float rw = __uint_as_float(sg & 0xffff0000u);
          float tb = __int_as_float(__builtin_amdgcn_ds_bpermute(
              (int)((sg & 63u) << 2), __float_as_int(treev)));
          float qd = bf2f(qdotL[(wv*16 + qloc)*68 + bucket]);
          float qm = (sg & 128u) ? -1e30f : qd;
          float p = exp2f(__builtin_fmaf(tb, rw, Scur[ct][r] + qm));
          if (d <= -32)      ts0[r] += p;
          else if (d >= 32)  ts1[r] += p;
          else             { rs[r] += p; PB[wv][qloc*96 + d + 32] = f2bf(p); }
          Pl[wv][qloc*40 + kloc] = f2bf(p);
        }
      }
    }

    // rotate sg: pkc <- tile jt+1, prefetch tile jt+2
    #pragma unroll
    for (int e = 0; e < 8; e++) pkc[e] = pk[e];
    {
      int kp = (jt + 2 < hi) ? ((jt + 2) << 5) : (lo << 5);
      #pragma unroll
      for (int e = 0; e < 8; e++) {
        int ct = e >> 2, r = e & 3;
        pk[e] = pkb[((q0 + quad*4 + r) << 10) + kp + ct*16 + l15];
      }
    }

    // ---- PV for tile jt
    {
      short8 aP = *(const short8*)&Pl[wv][l15*40 + quad*8];
      __builtin_amdgcn_s_setprio(1);
      #pragma unroll
      for (int t = 0; t < 4; t++)
        O[t] = __builtin_amdgcn_mfma_f32_16x16x32_bf16(aP, vreg[t], O[t], 0, 0, 0);
      __builtin_amdgcn_s_setprio(0);
    }

    if (jt < hi - 1) { Scur[0] = Sn0; Scur[1] = Sn1; }
  }

  // reduce partial sums across l15 lanes
  #pragma unroll
  for (int m = 1; m < 16; m <<= 1) {
    #pragma unroll
    for (int r = 0; r < 4; r++) {
      rs[r]  += __shfl_xor(rs[r],  m, 64);
      ts0[r] += __shfl_xor(ts0[r], m, 64);
      ts1[r] += __shfl_xor(ts1[r], m, 64);
    }
  }

  // banded relv contribution (PB slots 0/64 stay zero; far mass handled in k_comb)
  if (hasBand) {
    short8 aB[3];
    #pragma unroll
    for (int s = 0; s < 3; s++)
      aB[s] = *(const short8*)&PB[wv][l15*96 + s*32 + quad*8];
    #pragma unroll
    for (int t = 0; t < 4; t++)
      #pragma unroll
      for (int s = 0; s < 3; s++) {
        short8 bRV = *(const short8*)(relvT + (t*16 + l15)*96 + s*32 + quad*8);
        O[t] = __builtin_amdgcn_mfma_f32_16x16x32_bf16(aB[s], bRV, O[t], 0, 0, 0);
      }
  }

  // write partials
  {
    int rowb = (b*8 + h)*1024 + q0;
    float* op = opart + ((size_t)ks << 22) + (size_t)rowb*64;
    #pragma unroll
    for (int t = 0; t < 4; t++)
      #pragma unroll
      for (int r = 0; r < 4; r++)
        op[(quad*4 + r)*64 + t*16 + l15] = O[t][r];
    if (l15 == 0) {
      #pragma unroll
      for (int r = 0; r < 4; r++) {
        float4 s4 = make_float4(ts0[r], ts1[r], rs[r], 0.f);
        ((float4*)spart)[(ks << 16) + rowb + quad*4 + r] = s4;
      }
    }
  }
}

// ---------------- combine: O = O0+O1 + ts0*relv[0] + ts1*relv[64]; /rs ----
__global__ __launch_bounds__(256) void k_comb(const float* __restrict__ opart,
                                              const float* __restrict__ spart,
                                              const float* __restrict__ rev,
                                              u16* __restrict__ ctx) {
  int tid = threadIdx.x;
  int row = blockIdx.x * 16 + (tid >> 4);   // (b*8+h)*1024 + q
  int c = tid & 15;                          // float4 column
  float4 o0 = ((const float4*)opart)[(size_t)row*16 + c];
  float4 o1 = ((const float4*)opart)[(size_t)(65536 + row)*16 + c];
  float4 s0 = ((const float4*)spart)[row];
  float4 s1 = ((const float4*)spart)[65536 + row];
  float t0 = s0.x + s1.x, t1 = s0.y + s1.y;
  float inv = 1.0f / (s0.z + s1.z + t0 + t1);
  float4 rv0 = ((const float4*)rev)[c];             // rel_emb_v bucket 0
  float4 rv1 = ((const float4*)(rev + 64*64))[c];   // rel_emb_v bucket 64
  int b = row >> 13, h = (row >> 10) & 7, q = row & 1023;
  ushort4 o;
  o.x = f2bf((o0.x + o1.x + t0*rv0.x + t1*rv1.x) * inv);
  o.y = f2bf((o0.y + o1.y + t0*rv0.y + t1*rv1.y) * inv);
  o.z = f2bf((o0.z + o1.z + t0*rv0.z + t1*rv1.z) * inv);
  o.w = f2bf((o0.w + o1.w + t0*rv0.w + t1*rv1.w) * inv);
  *(ushort4*)(ctx + (size_t)(b*1024 + q)*512 + h*64 + c*4) = o;
}

extern "C" void kernel_launch(void* const* d_in, const int* in_sizes, int n_in,
                              void* d_out, int out_size, void* d_ws, size_t ws_size,
                              hipStream_t stream) {
  const float* key   = (const float*)d_in[0];
  const float* value = (const float*)d_in[1];
  const float* query = (const float*)d_in[2];
  const unsigned char* maskp = (const unsigned char*)d_in[3];
  const int*   relm  = (const int*)d_in[4];
  const float* relw  = (const float*)d_in[5];
  const float* Wk = (const float*)d_in[6];
  const float* bk = (const float*)d_in[7];
  const float* Wq = (const float*)d_in[8];
  const float* bq = (const float*)d_in[9];
  const float* Wv = (const float*)d_in[10];
  const float* bv = (const float*)d_in[11];
  const float* Wo = (const float*)d_in[12];
  const float* bo = (const float*)d_in[13];
  const float* rek = (const float*)d_in[14];
  const float* rev = (const float*)d_in[15];
  const float* te  = (const float*)d_in[16];
  (void)in_sizes; (void)n_in; (void)out_size;

  char* w = (char*)d_ws;
  size_t off = 0;
  auto alloc = [&](size_t bytes) -> void* {
    void* p = w + off; off += (bytes + 255) & ~(size_t)255; return p;
  };
  u16* WkT = (u16*)alloc((size_t)512*512*2);
  u16* WqT = (u16*)alloc((size_t)512*512*2);
  u16* WvT = (u16*)alloc((size_t)512*512*2);
  u16* WoT = (u16*)alloc((size_t)512*512*2);
  u16* qws = (u16*)alloc((size_t)8*8*1024*64*2);   // [B,H,L,64], pre-scaled 0.125*log2e
  u16* kws = (u16*)alloc((size_t)8*8*1024*64*2);   // [B,H,L,64]
  u16* vt  = (u16*)alloc((size_t)8*8*1024*64*2);   // [B,H,64,L]
  // 32MB region: first xq/xk/xv (bf16 inputs), later overwritten by packed —
  // safe: stream is serial; QKV gemms consume x* before k_pack writes.
  char* shared32 = (char*)alloc((size_t)8*1024*1024*4);
  u16* xq = (u16*)shared32;
  u16* xk = (u16*)(shared32 + (size_t)8192*512*2);
  u16* xv = (u16*)(shared32 + (size_t)2*8192*512*2);
  u32* packed = (u32*)shared32;
  u16* ctxb = (u16*)alloc((size_t)8192*512*2);     // [B,L,512] bf16
  u16* relk80 = (u16*)alloc((size_t)80*64*2);
  u16* relvT  = (u16*)alloc((size_t)64*96*2);
  float* opart = (float*)alloc((size_t)2*65536*64*4);  // [ks][b,h,q][64] f32
  float* spart = (float*)alloc((size_t)2*65536*4*4);   // [ks][b,h,q] float4
  if (off > ws_size) return;

  k_wt4<<<dim3(16,16,4), 256, 0, stream>>>(Wk, Wq, Wv, Wo, WkT, WqT, WvT, WoT);
  k_prep_rel<<<44, 256, 0, stream>>>(rek, rev, relk80, relvT);
  k_cvt3<<<dim3(4096,3), 256, 0, stream>>>(query, key, value, xq, xk, xv);

  // Q pre-scaled by 0.125 * log2(e): softmax computed in exp2 domain.
  GArg aq { xq, WqT, bq, (void*)qws, 1, 0.18033688f };
  GArg ak { xk, WkT, bk, (void*)kws, 1, 1.0f };
  GArg av { xv, WvT, bv, (void*)vt,  2, 1.0f };
  k_gemm<<<dim3(8,64,3), 256, 0, stream>>>(aq, ak, av);

  k_pack<<<8192, 256, 0, stream>>>(relm, relw, maskp, packed);

  k_attn<<<dim3(512,2,2), 256, 0, stream>>>(qws, kws, vt, relk80, relvT, te, packed,
                                            opart, spart);
  k_comb<<<4096, 256, 0, stream>>>(opart, spart, rev, ctxb);

  GArg ao { ctxb, WoT, bo, d_out, 0, 1.0f };
  k_gemm<<<dim3(8,64,1), 256, 0, stream>>>(ao, ao, ao);
}

// Round 5
// 337.382 us; speedup vs baseline: 1.2072x; 1.2072x over previous
//
#include <hip/hip_runtime.h>
#include <stdint.h>

using f32x4  = __attribute__((ext_vector_type(4))) float;
using short8 = __attribute__((ext_vector_type(8))) short;
typedef unsigned short u16;
typedef unsigned int   u32;

// B=8, H=8, L=1024, DM=512, DK=DV=64.  M = B*L = 8192.

static __device__ __forceinline__ u16 f2bf(float f) {
  union { float f; u32 u; } v; v.f = f;
  u32 r = v.u + 0x7fffu + ((v.u >> 16) & 1u);   // RNE
  return (u16)(r >> 16);
}
static __device__ __forceinline__ float bf2f(u16 u) {
  union { u32 u; float f; } v; v.u = ((u32)u) << 16;
  return v.f;
}

// async global->LDS, 16B per lane; LDS dest = wave-uniform base + lane*16
#define GLDS16(g, l) __builtin_amdgcn_global_load_lds( \
    (const __attribute__((address_space(1))) u32*)(g), \
    (__attribute__((address_space(3))) u32*)(l), 16, 0, 0)

// ------- 4 weight transposes in one launch: W [512k][512n] -> Wt [n][k] bf16
__global__ __launch_bounds__(256) void k_wt4(const float* __restrict__ W0, const float* __restrict__ W1,
                                             const float* __restrict__ W2, const float* __restrict__ W3,
                                             u16* __restrict__ T0, u16* __restrict__ T1,
                                             u16* __restrict__ T2, u16* __restrict__ T3) {
  const float* W = (blockIdx.z == 0) ? W0 : (blockIdx.z == 1) ? W1 : (blockIdx.z == 2) ? W2 : W3;
  u16* T = (blockIdx.z == 0) ? T0 : (blockIdx.z == 1) ? T1 : (blockIdx.z == 2) ? T2 : T3;
  __shared__ float t[32][33];
  int tx = threadIdx.x & 31, ty = threadIdx.x >> 5;   // 32 x 8
  int x0 = blockIdx.x * 32, y0 = blockIdx.y * 32;     // x = n, y = k
  #pragma unroll
  for (int i = 0; i < 4; i++)
    t[ty + i*8][tx] = W[(y0 + ty + i*8) * 512 + (x0 + tx)];
  __syncthreads();
  #pragma unroll
  for (int i = 0; i < 4; i++)
    T[(x0 + ty + i*8) * 512 + (y0 + tx)] = f2bf(t[tx][ty + i*8]);
}

// ------------- rel embeddings: relk80 [80][64] (zero-pad rows>=65),
//               relvT [64 dv][96 bucket] (zero-pad buckets>=65) -------------
__global__ __launch_bounds__(256) void k_prep_rel(const float* __restrict__ rk,
                                                  const float* __restrict__ rv,
                                                  u16* __restrict__ relk80,
                                                  u16* __restrict__ relvT) {
  int i = blockIdx.x * 256 + threadIdx.x;
  if (i < 80*64) {
    int row = i >> 6;
    relk80[i] = (row < 65) ? f2bf(rk[i]) : (u16)0;
  }
  int j = i - 80*64;
  if (j >= 0 && j < 64*96) {
    int dv = j / 96, bk = j % 96;
    relvT[j] = (bk < 65) ? f2bf(rv[bk*64 + dv]) : (u16)0;
  }
}

// ------------- fp32 -> bf16 for query/key/value in one launch -------------
__global__ __launch_bounds__(256) void k_cvt3(const float* __restrict__ a, const float* __restrict__ b,
                                              const float* __restrict__ c,
                                              u16* __restrict__ oa, u16* __restrict__ ob,
                                              u16* __restrict__ oc) {
  const float* src = (blockIdx.y == 0) ? a : (blockIdx.y == 1) ? b : c;
  u16* dst = (blockIdx.y == 0) ? oa : (blockIdx.y == 1) ? ob : oc;
  int i = blockIdx.x * 256 + threadIdx.x;
  float4 v = ((const float4*)src)[i];
  ushort4 o;
  o.x = f2bf(v.x); o.y = f2bf(v.y); o.z = f2bf(v.z); o.w = f2bf(v.w);
  ((ushort4*)dst)[i] = o;
}

// ------------- pack rel_matrix | mask<<7 | bf16(rel_mask)<<16 -> u32 -------
__global__ __launch_bounds__(256) void k_pack(const int* __restrict__ rm,
                                              const float* __restrict__ rw,
                                              const unsigned char* __restrict__ mk,
                                              u32* __restrict__ outp) {
  int i = blockIdx.x * 256 + threadIdx.x;     // x4 elements
  int4   r4 = ((const int4*)rm)[i];
  float4 w4 = ((const float4*)rw)[i];
  uchar4 m4 = ((const uchar4*)mk)[i];
  uint4 o;
  o.x = (u32)(r4.x & 63) | (m4.x ? 128u : 0u) | ((u32)f2bf(w4.x) << 16);
  o.y = (u32)(r4.y & 63) | (m4.y ? 128u : 0u) | ((u32)f2bf(w4.y) << 16);
  o.z = (u32)(r4.z & 63) | (m4.z ? 128u : 0u) | ((u32)f2bf(w4.z) << 16);
  o.w = (u32)(r4.w & 63) | (m4.w ? 128u : 0u) | ((u32)f2bf(w4.w) << 16);
  ((uint4*)outp)[i] = o;
}

// ---------------- bf16 MFMA GEMM: C = A[8192,512] @ Wt^T + bias -----------
struct GArg { const u16* A; const u16* Wt; const float* bias; void* out; int mode; float scale; };

__global__ __launch_bounds__(256) void k_gemm(GArg g0, GArg g1, GArg g2) {
  GArg ar = (blockIdx.z == 0) ? g0 : (blockIdx.z == 1) ? g1 : g2;
  __shared__ u16 As[128*32];   // chunk c (16B) at byte c*16: row=c>>2, slot=c&3
  __shared__ u16 Bs[64*32];
  __shared__ u16 Cs[9216];     // mode1: [128][72] pad; mode2 (transposed): [64][136] pad
  int tid = threadIdx.x, lane = tid & 63, wv = tid >> 6;
  int quad = lane >> 4, l15 = lane & 15;
  int n0 = blockIdx.x * 64, m0 = blockIdx.y * 128;
  int wm = (wv >> 1) * 64, wn = (wv & 1) * 32;
  f32x4 acc[4][2];
  #pragma unroll
  for (int i = 0; i < 4; i++)
    #pragma unroll
    for (int j = 0; j < 2; j++)
      acc[i][j] = (f32x4){0.f, 0.f, 0.f, 0.f};

  const u16* Abase = ar.A  + (size_t)m0 * 512;
  const u16* Bbase = ar.Wt + (size_t)n0 * 512;
  int cA0 = wv * 128, cB0 = wv * 64;      // wave-uniform chunk bases

  for (int k0 = 0; k0 < 512; k0 += 32) {
    #pragma unroll
    for (int i = 0; i < 2; i++) {
      int c = cA0 + i*64 + lane;
      GLDS16(Abase + (c >> 2)*512 + k0 + (c & 3)*8, &As[(cA0 + i*64)*8]);
    }
    {
      int c = cB0 + lane;
      GLDS16(Bbase + (c >> 2)*512 + k0 + (c & 3)*8, &Bs[cB0*8]);
    }
    __syncthreads();
    short8 af[4], bf[2];
    #pragma unroll
    for (int i = 0; i < 4; i++) af[i] = *(const short8*)&As[(wm + i*16 + l15)*32 + quad*8];
    #pragma unroll
    for (int j = 0; j < 2; j++) bf[j] = *(const short8*)&Bs[(wn + j*16 + l15)*32 + quad*8];
    #pragma unroll
    for (int i = 0; i < 4; i++)
      #pragma unroll
      for (int j = 0; j < 2; j++)
        acc[i][j] = __builtin_amdgcn_mfma_f32_16x16x32_bf16(af[i], bf[j], acc[i][j], 0, 0, 0);
    __syncthreads();
  }

  if (ar.mode == 0) {
    #pragma unroll
    for (int i = 0; i < 4; i++)
      #pragma unroll
      for (int j = 0; j < 2; j++) {
        int ncol = n0 + wn + j*16 + l15;
        float bv = ar.bias[ncol];
        #pragma unroll
        for (int r = 0; r < 4; r++) {
          int m = m0 + wm + i*16 + quad*4 + r;
          ((float*)ar.out)[m*512 + ncol] = (acc[i][j][r] + bv) * ar.scale;
        }
      }
  } else {
    #pragma unroll
    for (int i = 0; i < 4; i++)
      #pragma unroll
      for (int j = 0; j < 2; j++) {
        int nloc = wn + j*16 + l15;
        float bv = ar.bias[n0 + nloc];
        #pragma unroll
        for (int r = 0; r < 4; r++) {
          int mloc = wm + i*16 + quad*4 + r;
          float val = (acc[i][j][r] + bv) * ar.scale;
          if (ar.mode == 1) Cs[mloc*72 + nloc] = f2bf(val);
          else              Cs[nloc*136 + mloc] = f2bf(val);
        }
      }
    __syncthreads();
    int bb = m0 >> 10, hh = n0 >> 6, mbase = m0 & 1023;
    u16* outp = (u16*)ar.out;
    if (ar.mode == 1) {
      size_t base = ((size_t)(bb*8 + hh)*1024 + mbase)*64;
      #pragma unroll
      for (int p = 0; p < 4; p++) {
        int mloc = (tid >> 3) + p*32, seg = tid & 7;
        *(short8*)(outp + base + (size_t)mloc*64 + seg*8) = *(const short8*)&Cs[mloc*72 + seg*8];
      }
    } else {
      size_t base = (size_t)(bb*8 + hh)*64*1024 + mbase;
      #pragma unroll
      for (int p = 0; p < 4; p++) {
        int d = (tid >> 4) + p*16, seg = tid & 15;
        *(short8*)(outp + base + (size_t)d*1024 + seg*8) = *(const short8*)&Cs[d*136 + seg*8];
      }
    }
  }
}

// ---------------- fused attention ----------------
// R10: block = one (b, head, 64 q-rows); 4 waves = 4 q-tiles of the SAME
// head -> K/V tiles shared across waves, staged to LDS via global_load_lds
// (2 issues/wave/tile), double-buffered, ONE barrier per tile (stage issued
// AFTER the barrier so prior-iteration readers of the dest buffer are done).
// K/V fragment reads are ds_read_b128 at precomputed offsets (+imm) -- the
// per-tile K/V address VALU and 12 scattered global loads of R7-R9 are gone
// (R9 falsified wave-supply: occupancy pinned at 28% regardless of grid ->
// stall-bound waves; this attacks the stalls + inst count directly).
// Swizzles (both-sides, rule #21): K rows 128B, byte ^= ((row&7)<<4);
// V rows 64B, byte ^= ((row&3)<<4). Both read patterns hit the b128 floor.
__global__ __launch_bounds__(256, 3) void k_attn(
    const u16* __restrict__ qws, const u16* __restrict__ kws, const u16* __restrict__ vtws,
    const u16* __restrict__ relk80, const u16* __restrict__ relvT,
    const float* __restrict__ tree_emb, const u32* __restrict__ packed,
    u16* __restrict__ ctx) {
  __shared__ u16 Kb[2][2048];       // [buf][32 k-rows][64 d] swizzled
  __shared__ u16 Vb[2][2048];       // [buf][64 d-rows][32 k] swizzled
  __shared__ u16 qdotL[4*16*68];    // [w][q][bucket]  (band tiles)
  __shared__ u16 PB[4][16*96];      // per-wave banded P
  __shared__ u16 Pl[4][16*40];      // per-wave C->A bridge, stride 40

  int tid = threadIdx.x, lane = tid & 63, wv = tid >> 6;
  int quad = lane >> 4, l15 = lane & 15;
  int qb = blockIdx.x, h = blockIdx.y, b = blockIdx.z;
  int q0 = qb * 64 + wv * 16;

  // register tree table: lane v (0..63) holds tree_emb[v][h] * log2e
  float treev = tree_emb[lane * 8 + h] * 1.44269504f;

  #pragma unroll
  for (int i = 0; i < 12; i++) ((u32*)&PB[wv][0])[lane + i*64] = 0u;

  const u16* qp = qws  + (size_t)(b*8 + h)*(1024*64);
  const u16* kp = kws  + (size_t)(b*8 + h)*(1024*64);
  const u16* vp = vtws + (size_t)(b*8 + h)*(64*1024);
  const u32* pkb = packed + ((size_t)b << 20);

  short8 aQ[2];
  #pragma unroll
  for (int kf = 0; kf < 2; kf++)
    aQ[kf] = *(const short8*)(qp + (q0 + l15)*64 + kf*32 + quad*8);

  float qd0[4], qd64[4];
  #pragma unroll
  for (int t = 0; t < 5; t++) {
    f32x4 C = (f32x4){0.f,0.f,0.f,0.f};
    #pragma unroll
    for (int kf = 0; kf < 2; kf++) {
      short8 bR = *(const short8*)(relk80 + (t*16 + l15)*64 + kf*32 + quad*8);
      C = __builtin_amdgcn_mfma_f32_16x16x32_bf16(aQ[kf], bR, C, 0, 0, 0);
    }
    if (t == 0) {
      #pragma unroll
      for (int r = 0; r < 4; r++) qd0[r] = __shfl(C[r], lane & 48, 64);
    }
    if (t == 4) {
      #pragma unroll
      for (int r = 0; r < 4; r++) qd64[r] = __shfl(C[r], lane & 48, 64);
    }
    int col = t*16 + l15;
    if (col < 65) {
      #pragma unroll
      for (int r = 0; r < 4; r++)
        qdotL[(wv*16 + quad*4 + r)*68 + col] = f2bf(C[r]);
    }
  }

  int t_lo = max(0, (q0 - 31) >> 5);
  int t_hi = min(31, (q0 + 46) >> 5);

  // precomputed LDS read offsets (u16 units); ct adds 1024, t adds 512
  int sK = (l15 & 7) << 3;
  int kbo0 = l15*64 + ((quad*8) ^ sK);          // kf=0: 8*(quad ^ (l15&7))
  int kbo1 = l15*64 + (((4 + quad)*8) ^ sK);    // kf=1: 8*((4+quad) ^ (l15&7))
  int vbo  = l15*32 + ((quad*8) ^ ((l15 & 3) << 3));

  // staging: wave wv carries K rows wv*8..+7 and V rows wv*16..+15 of the tile
  int rk = wv*8 + (lane >> 3);
  int swk = (((lane & 7)*8) ^ ((rk & 7) << 3));
  int rv = wv*16 + (lane >> 2);
  const u16* vsrc = vp + (size_t)rv*1024 + (((lane & 3)*8) ^ ((rv & 3) << 3));

#define STAGE(kt, nb) do { \
    GLDS16(kp + (size_t)((kt)*32 + rk)*64 + swk, &Kb[nb][wv*512]); \
    GLDS16(vsrc + (kt)*32, &Vb[nb][wv*512]); \
  } while (0)

  STAGE(0, 0);

  u32 pk[8];
  #pragma unroll
  for (int e = 0; e < 8; e++)
    pk[e] = pkb[((q0 + quad*4 + (e & 3)) << 10) + (e >> 2)*16 + l15];

  f32x4 O[4];
  float rs[4], ts0[4], ts1[4];
  #pragma unroll
  for (int t = 0; t < 4; t++) O[t] = (f32x4){0.f,0.f,0.f,0.f};
  #pragma unroll
  for (int r = 0; r < 4; r++) { rs[r] = 0.f; ts0[r] = 0.f; ts1[r] = 0.f; }

  for (int jt = 0; jt < 32; ++jt) {
    int cur = jt & 1;
    int k0 = jt << 5;
    __syncthreads();                    // stage(jt) complete; readers of buf cur^1 done
    if (jt < 31) STAGE(jt + 1, cur ^ 1);

    u32 pkc[8];
    #pragma unroll
    for (int e = 0; e < 8; e++) pkc[e] = pk[e];
    if (jt < 31) {
      int kn = (jt + 1) << 5;
      #pragma unroll
      for (int e = 0; e < 8; e++)
        pk[e] = pkb[((q0 + quad*4 + (e & 3)) << 10) + kn + (e >> 2)*16 + l15];
    }

    short8 kr00 = *(const short8*)&Kb[cur][kbo0];
    short8 kr01 = *(const short8*)&Kb[cur][kbo1];
    short8 kr10 = *(const short8*)&Kb[cur][1024 + kbo0];
    short8 kr11 = *(const short8*)&Kb[cur][1024 + kbo1];
    short8 vr[4];
    #pragma unroll
    for (int t = 0; t < 4; t++) vr[t] = *(const short8*)&Vb[cur][t*512 + vbo];

    f32x4 S0 = (f32x4){0.f,0.f,0.f,0.f}, S1 = (f32x4){0.f,0.f,0.f,0.f};
    __builtin_amdgcn_s_setprio(1);
    S0 = __builtin_amdgcn_mfma_f32_16x16x32_bf16(aQ[0], kr00, S0, 0, 0, 0);
    S0 = __builtin_amdgcn_mfma_f32_16x16x32_bf16(aQ[1], kr01, S0, 0, 0, 0);
    S1 = __builtin_amdgcn_mfma_f32_16x16x32_bf16(aQ[0], kr10, S1, 0, 0, 0);
    S1 = __builtin_amdgcn_mfma_f32_16x16x32_bf16(aQ[1], kr11, S1, 0, 0, 0);
    __builtin_amdgcn_s_setprio(0);
    f32x4 Scur[2] = { S0, S1 };

    if (jt < t_lo) {
      #pragma unroll
      for (int ct = 0; ct < 2; ct++) {
        #pragma unroll
        for (int r = 0; r < 4; r++) {
          u32 sg = pkc[ct*4 + r];
          float rw = __uint_as_float(sg & 0xffff0000u);
          float tb = __int_as_float(__builtin_amdgcn_ds_bpermute(
              (int)((sg & 63u) << 2), __float_as_int(treev)));
          float qm = (sg & 128u) ? -1e30f : qd0[r];
          float p = exp2f(__builtin_fmaf(tb, rw, Scur[ct][r] + qm));
          ts0[r] += p;
          Pl[wv][(quad*4 + r)*40 + ct*16 + l15] = f2bf(p);
        }
      }
    } else if (jt > t_hi) {
      #pragma unroll
      for (int ct = 0; ct < 2; ct++) {
        #pragma unroll
        for (int r = 0; r < 4; r++) {
          u32 sg = pkc[ct*4 + r];
          float rw = __uint_as_float(sg & 0xffff0000u);
          float tb = __int_as_float(__builtin_amdgcn_ds_bpermute(
              (int)((sg & 63u) << 2), __float_as_int(treev)));
          float qm = (sg & 128u) ? -1e30f : qd64[r];
          float p = exp2f(__builtin_fmaf(tb, rw, Scur[ct][r] + qm));
          ts1[r] += p;
          Pl[wv][(quad*4 + r)*40 + ct*16 + l15] = f2bf(p);
        }
      }
    } else {
      #pragma unroll
      for (int ct = 0; ct < 2; ct++) {
        #pragma unroll
        for (int r = 0; r < 4; r++) {
          int kloc = ct*16 + l15, qloc = quad*4 + r;
          int d = (k0 + kloc) - (q0 + qloc);
          int bucket = min(max(d + 32, 0), 64);
          u32 sg = pkc[ct*4 + r];
          float rw = __uint_as_float(sg & 0xffff0000u);
          float tb = __int_as_float(__builtin_amdgcn_ds_bpermute(
              (int)((sg & 63u) << 2), __float_as_int(treev)));
          float qd = bf2f(qdotL[(wv*16 + qloc)*68 + bucket]);
          float qm = (sg & 128u) ? -1e30f : qd;
          float p = exp2f(__builtin_fmaf(tb, rw, Scur[ct][r] + qm));
          if (d <= -32)      ts0[r] += p;
          else if (d >= 32)  ts1[r] += p;
          else             { rs[r] += p; PB[wv][qloc*96 + d + 32] = f2bf(p); }
          Pl[wv][qloc*40 + kloc] = f2bf(p);
        }
      }
    }

    {
      short8 aP = *(const short8*)&Pl[wv][l15*40 + quad*8];
      __builtin_amdgcn_s_setprio(1);
      #pragma unroll
      for (int t = 0; t < 4; t++)
        O[t] = __builtin_amdgcn_mfma_f32_16x16x32_bf16(aP, vr[t], O[t], 0, 0, 0);
      __builtin_amdgcn_s_setprio(0);
    }
  }
#undef STAGE

  #pragma unroll
  for (int m = 1; m < 16; m <<= 1) {
    #pragma unroll
    for (int r = 0; r < 4; r++) {
      rs[r]  += __shfl_xor(rs[r],  m, 64);
      ts0[r] += __shfl_xor(ts0[r], m, 64);
      ts1[r] += __shfl_xor(ts1[r], m, 64);
    }
  }
  if (l15 == 0) {
    #pragma unroll
    for (int r = 0; r < 4; r++) {
      PB[wv][(quad*4 + r)*96 + 0]  = f2bf(ts0[r]);
      PB[wv][(quad*4 + r)*96 + 64] = f2bf(ts1[r]);
    }
  }
  // PB is per-wave: ds_write -> ds_read within the same wave, no barrier.

  {
    short8 aB[3];
    #pragma unroll
    for (int s = 0; s < 3; s++)
      aB[s] = *(const short8*)&PB[wv][l15*96 + s*32 + quad*8];
    #pragma unroll
    for (int t = 0; t < 4; t++)
      #pragma unroll
      for (int s = 0; s < 3; s++) {
        short8 bRV = *(const short8*)(relvT + (t*16 + l15)*96 + s*32 + quad*8);
        O[t] = __builtin_amdgcn_mfma_f32_16x16x32_bf16(aB[s], bRV, O[t], 0, 0, 0);
      }
  }

  {
    float inv[4];
    #pragma unroll
    for (int r = 0; r < 4; r++) inv[r] = 1.0f / (rs[r] + ts0[r] + ts1[r]);
    #pragma unroll
    for (int t = 0; t < 4; t++)
      #pragma unroll
      for (int r = 0; r < 4; r++) {
        int qg = q0 + quad*4 + r;
        ctx[(b*1024 + qg)*512 + h*64 + t*16 + l15] = f2bf(O[t][r] * inv[r]);
      }
  }
}

extern "C" void kernel_launch(void* const* d_in, const int* in_sizes, int n_in,
                              void* d_out, int out_size, void* d_ws, size_t ws_size,
                              hipStream_t stream) {
  const float* key   = (const float*)d_in[0];
  const float* value = (const float*)d_in[1];
  const float* query = (const float*)d_in[2];
  const unsigned char* maskp = (const unsigned char*)d_in[3];
  const int*   relm  = (const int*)d_in[4];
  const float* relw  = (const float*)d_in[5];
  const float* Wk = (const float*)d_in[6];
  const float* bk = (const float*)d_in[7];
  const float* Wq = (const float*)d_in[8];
  const float* bq = (const float*)d_in[9];
  const float* Wv = (const float*)d_in[10];
  const float* bv = (const float*)d_in[11];
  const float* Wo = (const float*)d_in[12];
  const float* bo = (const float*)d_in[13];
  const float* rek = (const float*)d_in[14];
  const float* rev = (const float*)d_in[15];
  const float* te  = (const float*)d_in[16];
  (void)in_sizes; (void)n_in; (void)out_size;

  char* w = (char*)d_ws;
  size_t off = 0;
  auto alloc = [&](size_t bytes) -> void* {
    void* p = w + off; off += (bytes + 255) & ~(size_t)255; return p;
  };
  u16* WkT = (u16*)alloc((size_t)512*512*2);
  u16* WqT = (u16*)alloc((size_t)512*512*2);
  u16* WvT = (u16*)alloc((size_t)512*512*2);
  u16* WoT = (u16*)alloc((size_t)512*512*2);
  u16* qws = (u16*)alloc((size_t)8*8*1024*64*2);   // [B,H,L,64], pre-scaled 0.125*log2e
  u16* kws = (u16*)alloc((size_t)8*8*1024*64*2);   // [B,H,L,64]
  u16* vt  = (u16*)alloc((size_t)8*8*1024*64*2);   // [B,H,64,L]
  // 32MB region: first xq/xk/xv (bf16 inputs), later overwritten by packed —
  // safe: stream is serial; QKV gemms consume x* before k_pack writes.
  char* shared32 = (char*)alloc((size_t)8*1024*1024*4);
  u16* xq = (u16*)shared32;
  u16* xk = (u16*)(shared32 + (size_t)8192*512*2);
  u16* xv = (u16*)(shared32 + (size_t)2*8192*512*2);
  u32* packed = (u32*)shared32;
  u16* ctxb = (u16*)alloc((size_t)8192*512*2);     // [B,L,512] bf16
  u16* relk80 = (u16*)alloc((size_t)80*64*2);
  u16* relvT  = (u16*)alloc((size_t)64*96*2);
  if (off > ws_size) return;

  k_wt4<<<dim3(16,16,4), 256, 0, stream>>>(Wk, Wq, Wv, Wo, WkT, WqT, WvT, WoT);
  k_prep_rel<<<44, 256, 0, stream>>>(rek, rev, relk80, relvT);
  k_cvt3<<<dim3(4096,3), 256, 0, stream>>>(query, key, value, xq, xk, xv);

  // Q pre-scaled by 0.125 * log2(e): softmax computed in exp2 domain.
  GArg aq { xq, WqT, bq, (void*)qws, 1, 0.18033688f };
  GArg ak { xk, WkT, bk, (void*)kws, 1, 1.0f };
  GArg av { xv, WvT, bv, (void*)vt,  2, 1.0f };
  k_gemm<<<dim3(8,64,3), 256, 0, stream>>>(aq, ak, av);

  k_pack<<<8192, 256, 0, stream>>>(relm, relw, maskp, packed);

  k_attn<<<dim3(16,8,8), 256, 0, stream>>>(qws, kws, vt, relk80, relvT, te, packed, ctxb);

  GArg ao { ctxb, WoT, bo, d_out, 0, 1.0f };
  k_gemm<<<dim3(8,64,1), 256, 0, stream>>>(ao, ao, ao);
}

// Round 6
// 320.103 us; speedup vs baseline: 1.2724x; 1.0540x over previous
//
#include <hip/hip_runtime.h>
#include <stdint.h>

using f32x4  = __attribute__((ext_vector_type(4))) float;
using short8 = __attribute__((ext_vector_type(8))) short;
typedef unsigned short u16;
typedef unsigned int   u32;

// B=8, H=8, L=1024, DM=512, DK=DV=64.  M = B*L = 8192.

static __device__ __forceinline__ u16 f2bf(float f) {
  union { float f; u32 u; } v; v.f = f;
  u32 r = v.u + 0x7fffu + ((v.u >> 16) & 1u);   // RNE
  return (u16)(r >> 16);
}
static __device__ __forceinline__ float bf2f(u16 u) {
  union { u32 u; float f; } v; v.u = ((u32)u) << 16;
  return v.f;
}

// async global->LDS, 16B per lane; LDS dest = wave-uniform base + lane*16
#define GLDS16(g, l) __builtin_amdgcn_global_load_lds( \
    (const __attribute__((address_space(1))) u32*)(g), \
    (__attribute__((address_space(3))) u32*)(l), 16, 0, 0)

// ------- 4 weight transposes in one launch: W [512k][512n] -> Wt [n][k] bf16
__global__ __launch_bounds__(256) void k_wt4(const float* __restrict__ W0, const float* __restrict__ W1,
                                             const float* __restrict__ W2, const float* __restrict__ W3,
                                             u16* __restrict__ T0, u16* __restrict__ T1,
                                             u16* __restrict__ T2, u16* __restrict__ T3) {
  const float* W = (blockIdx.z == 0) ? W0 : (blockIdx.z == 1) ? W1 : (blockIdx.z == 2) ? W2 : W3;
  u16* T = (blockIdx.z == 0) ? T0 : (blockIdx.z == 1) ? T1 : (blockIdx.z == 2) ? T2 : T3;
  __shared__ float t[32][33];
  int tx = threadIdx.x & 31, ty = threadIdx.x >> 5;   // 32 x 8
  int x0 = blockIdx.x * 32, y0 = blockIdx.y * 32;     // x = n, y = k
  #pragma unroll
  for (int i = 0; i < 4; i++)
    t[ty + i*8][tx] = W[(y0 + ty + i*8) * 512 + (x0 + tx)];
  __syncthreads();
  #pragma unroll
  for (int i = 0; i < 4; i++)
    T[(x0 + ty + i*8) * 512 + (y0 + tx)] = f2bf(t[tx][ty + i*8]);
}

// ------------- rel embeddings: relk80 [80][64] (zero-pad rows>=65),
//               relvT [64 dv][96 bucket] (zero-pad buckets>=65) -------------
__global__ __launch_bounds__(256) void k_prep_rel(const float* __restrict__ rk,
                                                  const float* __restrict__ rv,
                                                  u16* __restrict__ relk80,
                                                  u16* __restrict__ relvT) {
  int i = blockIdx.x * 256 + threadIdx.x;
  if (i < 80*64) {
    int row = i >> 6;
    relk80[i] = (row < 65) ? f2bf(rk[i]) : (u16)0;
  }
  int j = i - 80*64;
  if (j >= 0 && j < 64*96) {
    int dv = j / 96, bk = j % 96;
    relvT[j] = (bk < 65) ? f2bf(rv[bk*64 + dv]) : (u16)0;
  }
}

// ------------- fp32 -> bf16 for query/key/value in one launch -------------
__global__ __launch_bounds__(256) void k_cvt3(const float* __restrict__ a, const float* __restrict__ b,
                                              const float* __restrict__ c,
                                              u16* __restrict__ oa, u16* __restrict__ ob,
                                              u16* __restrict__ oc) {
  const float* src = (blockIdx.y == 0) ? a : (blockIdx.y == 1) ? b : c;
  u16* dst = (blockIdx.y == 0) ? oa : (blockIdx.y == 1) ? ob : oc;
  int i = blockIdx.x * 256 + threadIdx.x;
  float4 v = ((const float4*)src)[i];
  ushort4 o;
  o.x = f2bf(v.x); o.y = f2bf(v.y); o.z = f2bf(v.z); o.w = f2bf(v.w);
  ((ushort4*)dst)[i] = o;
}

// ------------- pack rel_matrix | mask<<7 | bf16(rel_mask)<<16 -> u32 -------
__global__ __launch_bounds__(256) void k_pack(const int* __restrict__ rm,
                                              const float* __restrict__ rw,
                                              const unsigned char* __restrict__ mk,
                                              u32* __restrict__ outp) {
  int i = blockIdx.x * 256 + threadIdx.x;     // x4 elements
  int4   r4 = ((const int4*)rm)[i];
  float4 w4 = ((const float4*)rw)[i];
  uchar4 m4 = ((const uchar4*)mk)[i];
  uint4 o;
  o.x = (u32)(r4.x & 63) | (m4.x ? 128u : 0u) | ((u32)f2bf(w4.x) << 16);
  o.y = (u32)(r4.y & 63) | (m4.y ? 128u : 0u) | ((u32)f2bf(w4.y) << 16);
  o.z = (u32)(r4.z & 63) | (m4.z ? 128u : 0u) | ((u32)f2bf(w4.z) << 16);
  o.w = (u32)(r4.w & 63) | (m4.w ? 128u : 0u) | ((u32)f2bf(w4.w) << 16);
  ((uint4*)outp)[i] = o;
}

// ---------------- bf16 MFMA GEMM: C = A[8192,512] @ Wt^T + bias -----------
struct GArg { const u16* A; const u16* Wt; const float* bias; void* out; int mode; float scale; };

__global__ __launch_bounds__(256) void k_gemm(GArg g0, GArg g1, GArg g2) {
  GArg ar = (blockIdx.z == 0) ? g0 : (blockIdx.z == 1) ? g1 : g2;
  __shared__ u16 As[128*32];   // chunk c (16B) at byte c*16: row=c>>2, slot=c&3
  __shared__ u16 Bs[64*32];
  __shared__ u16 Cs[9216];     // mode1: [128][72] pad; mode2 (transposed): [64][136] pad
  int tid = threadIdx.x, lane = tid & 63, wv = tid >> 6;
  int quad = lane >> 4, l15 = lane & 15;
  int n0 = blockIdx.x * 64, m0 = blockIdx.y * 128;
  int wm = (wv >> 1) * 64, wn = (wv & 1) * 32;
  f32x4 acc[4][2];
  #pragma unroll
  for (int i = 0; i < 4; i++)
    #pragma unroll
    for (int j = 0; j < 2; j++)
      acc[i][j] = (f32x4){0.f, 0.f, 0.f, 0.f};

  const u16* Abase = ar.A  + (size_t)m0 * 512;
  const u16* Bbase = ar.Wt + (size_t)n0 * 512;
  int cA0 = wv * 128, cB0 = wv * 64;      // wave-uniform chunk bases

  for (int k0 = 0; k0 < 512; k0 += 32) {
    #pragma unroll
    for (int i = 0; i < 2; i++) {
      int c = cA0 + i*64 + lane;
      GLDS16(Abase + (c >> 2)*512 + k0 + (c & 3)*8, &As[(cA0 + i*64)*8]);
    }
    {
      int c = cB0 + lane;
      GLDS16(Bbase + (c >> 2)*512 + k0 + (c & 3)*8, &Bs[cB0*8]);
    }
    __syncthreads();
    short8 af[4], bf[2];
    #pragma unroll
    for (int i = 0; i < 4; i++) af[i] = *(const short8*)&As[(wm + i*16 + l15)*32 + quad*8];
    #pragma unroll
    for (int j = 0; j < 2; j++) bf[j] = *(const short8*)&Bs[(wn + j*16 + l15)*32 + quad*8];
    #pragma unroll
    for (int i = 0; i < 4; i++)
      #pragma unroll
      for (int j = 0; j < 2; j++)
        acc[i][j] = __builtin_amdgcn_mfma_f32_16x16x32_bf16(af[i], bf[j], acc[i][j], 0, 0, 0);
    __syncthreads();
  }

  if (ar.mode == 0) {
    #pragma unroll
    for (int i = 0; i < 4; i++)
      #pragma unroll
      for (int j = 0; j < 2; j++) {
        int ncol = n0 + wn + j*16 + l15;
        float bv = ar.bias[ncol];
        #pragma unroll
        for (int r = 0; r < 4; r++) {
          int m = m0 + wm + i*16 + quad*4 + r;
          ((float*)ar.out)[m*512 + ncol] = (acc[i][j][r] + bv) * ar.scale;
        }
      }
  } else {
    #pragma unroll
    for (int i = 0; i < 4; i++)
      #pragma unroll
      for (int j = 0; j < 2; j++) {
        int nloc = wn + j*16 + l15;
        float bv = ar.bias[n0 + nloc];
        #pragma unroll
        for (int r = 0; r < 4; r++) {
          int mloc = wm + i*16 + quad*4 + r;
          float val = (acc[i][j][r] + bv) * ar.scale;
          if (ar.mode == 1) Cs[mloc*72 + nloc] = f2bf(val);
          else              Cs[nloc*136 + mloc] = f2bf(val);
        }
      }
    __syncthreads();
    int bb = m0 >> 10, hh = n0 >> 6, mbase = m0 & 1023;
    u16* outp = (u16*)ar.out;
    if (ar.mode == 1) {
      size_t base = ((size_t)(bb*8 + hh)*1024 + mbase)*64;
      #pragma unroll
      for (int p = 0; p < 4; p++) {
        int mloc = (tid >> 3) + p*32, seg = tid & 7;
        *(short8*)(outp + base + (size_t)mloc*64 + seg*8) = *(const short8*)&Cs[mloc*72 + seg*8];
      }
    } else {
      size_t base = (size_t)(bb*8 + hh)*64*1024 + mbase;
      #pragma unroll
      for (int p = 0; p < 4; p++) {
        int d = (tid >> 4) + p*16, seg = tid & 15;
        *(short8*)(outp + base + (size_t)d*1024 + seg*8) = *(const short8*)&Cs[d*136 + seg*8];
      }
    }
  }
}

// ---------------- fused attention ----------------
// R11: 8-wave blocks. R10 showed LDS 42.5KB -> 3 blocks/CU but grid needs
// 4/CU: ragged 3+1 tail, Occupancy 24%; and each 64-row block re-staged the
// whole K/V (FETCH 86MB). Now block = (b, h, 128 q-rows), 512 threads:
// waves 0-3 stage K tile, waves 4-7 stage V tile (1 GLDS16/wave/tile, K/V
// shared by 8 waves), per-wave qdotL/PB/Pl doubled. LDS 67KB -> exactly
// 2 blocks/CU, grid 512 = exactly 2/CU (no tail), 16 waves/CU.
// VGPR 72 fits the 128 cap of (512,4) -- no spill risk (R6 trap re-checked).
__global__ __launch_bounds__(512, 4) void k_attn(
    const u16* __restrict__ qws, const u16* __restrict__ kws, const u16* __restrict__ vtws,
    const u16* __restrict__ relk80, const u16* __restrict__ relvT,
    const float* __restrict__ tree_emb, const u32* __restrict__ packed,
    u16* __restrict__ ctx) {
  __shared__ u16 Kb[2][2048];       // [buf][32 k-rows][64 d] swizzled
  __shared__ u16 Vb[2][2048];       // [buf][64 d-rows][32 k] swizzled
  __shared__ u16 qdotL[8*16*68];    // [w][q][bucket]  (band tiles)
  __shared__ u16 PB[8][16*96];      // per-wave banded P
  __shared__ u16 Pl[8][16*40];      // per-wave C->A bridge, stride 40

  int tid = threadIdx.x, lane = tid & 63, wv = tid >> 6;
  int quad = lane >> 4, l15 = lane & 15;
  int qb = blockIdx.x, h = blockIdx.y, b = blockIdx.z;
  int q0 = qb * 128 + wv * 16;

  // register tree table: lane v (0..63) holds tree_emb[v][h] * log2e
  float treev = tree_emb[lane * 8 + h] * 1.44269504f;

  #pragma unroll
  for (int i = 0; i < 12; i++) ((u32*)&PB[wv][0])[lane + i*64] = 0u;

  const u16* qp = qws  + (size_t)(b*8 + h)*(1024*64);
  const u16* kp = kws  + (size_t)(b*8 + h)*(1024*64);
  const u16* vp = vtws + (size_t)(b*8 + h)*(64*1024);
  const u32* pkb = packed + ((size_t)b << 20);

  // staging roles: waves 0-3 carry K rows wv*8..+7; waves 4-7 carry V rows
  // (wv-4)*16..+15 of each 32-key tile.
  int rk = (wv & 3)*8 + (lane >> 3);
  int swk = (((lane & 7)*8) ^ ((rk & 7) << 3));
  int rv = (wv & 3)*16 + (lane >> 2);
  const u16* vsrc = vp + (size_t)rv*1024 + (((lane & 3)*8) ^ ((rv & 3) << 3));

#define STAGE(kt, nb) do { \
    if (wv < 4) GLDS16(kp + (size_t)((kt)*32 + rk)*64 + swk, &Kb[nb][wv*512]); \
    else        GLDS16(vsrc + (kt)*32, &Vb[nb][(wv & 3)*512]); \
  } while (0)

  STAGE(0, 0);

  short8 aQ[2];
  #pragma unroll
  for (int kf = 0; kf < 2; kf++)
    aQ[kf] = *(const short8*)(qp + (q0 + l15)*64 + kf*32 + quad*8);

  float qd0[4], qd64[4];
  #pragma unroll
  for (int t = 0; t < 5; t++) {
    f32x4 C = (f32x4){0.f,0.f,0.f,0.f};
    #pragma unroll
    for (int kf = 0; kf < 2; kf++) {
      short8 bR = *(const short8*)(relk80 + (t*16 + l15)*64 + kf*32 + quad*8);
      C = __builtin_amdgcn_mfma_f32_16x16x32_bf16(aQ[kf], bR, C, 0, 0, 0);
    }
    if (t == 0) {
      #pragma unroll
      for (int r = 0; r < 4; r++) qd0[r] = __shfl(C[r], lane & 48, 64);
    }
    if (t == 4) {
      #pragma unroll
      for (int r = 0; r < 4; r++) qd64[r] = __shfl(C[r], lane & 48, 64);
    }
    int col = t*16 + l15;
    if (col < 65) {
      #pragma unroll
      for (int r = 0; r < 4; r++)
        qdotL[(wv*16 + quad*4 + r)*68 + col] = f2bf(C[r]);
    }
  }

  int t_lo = max(0, (q0 - 31) >> 5);
  int t_hi = min(31, (q0 + 46) >> 5);

  // precomputed LDS read offsets (u16 units); ct adds 1024, t adds 512
  int sK = (l15 & 7) << 3;
  int kbo0 = l15*64 + ((quad*8) ^ sK);          // kf=0
  int kbo1 = l15*64 + (((4 + quad)*8) ^ sK);    // kf=1
  int vbo  = l15*32 + ((quad*8) ^ ((l15 & 3) << 3));

  u32 pk[8];
  #pragma unroll
  for (int e = 0; e < 8; e++)
    pk[e] = pkb[((q0 + quad*4 + (e & 3)) << 10) + (e >> 2)*16 + l15];

  f32x4 O[4];
  float rs[4], ts0[4], ts1[4];
  #pragma unroll
  for (int t = 0; t < 4; t++) O[t] = (f32x4){0.f,0.f,0.f,0.f};
  #pragma unroll
  for (int r = 0; r < 4; r++) { rs[r] = 0.f; ts0[r] = 0.f; ts1[r] = 0.f; }

  for (int jt = 0; jt < 32; ++jt) {
    int cur = jt & 1;
    int k0 = jt << 5;
    __syncthreads();                    // stage(jt) complete; readers of buf cur^1 done
    if (jt < 31) STAGE(jt + 1, cur ^ 1);

    u32 pkc[8];
    #pragma unroll
    for (int e = 0; e < 8; e++) pkc[e] = pk[e];
    if (jt < 31) {
      int kn = (jt + 1) << 5;
      #pragma unroll
      for (int e = 0; e < 8; e++)
        pk[e] = pkb[((q0 + quad*4 + (e & 3)) << 10) + kn + (e >> 2)*16 + l15];
    }

    short8 kr00 = *(const short8*)&Kb[cur][kbo0];
    short8 kr01 = *(const short8*)&Kb[cur][kbo1];
    short8 kr10 = *(const short8*)&Kb[cur][1024 + kbo0];
    short8 kr11 = *(const short8*)&Kb[cur][1024 + kbo1];
    short8 vr[4];
    #pragma unroll
    for (int t = 0; t < 4; t++) vr[t] = *(const short8*)&Vb[cur][t*512 + vbo];

    f32x4 S0 = (f32x4){0.f,0.f,0.f,0.f}, S1 = (f32x4){0.f,0.f,0.f,0.f};
    __builtin_amdgcn_s_setprio(1);
    S0 = __builtin_amdgcn_mfma_f32_16x16x32_bf16(aQ[0], kr00, S0, 0, 0, 0);
    S0 = __builtin_amdgcn_mfma_f32_16x16x32_bf16(aQ[1], kr01, S0, 0, 0, 0);
    S1 = __builtin_amdgcn_mfma_f32_16x16x32_bf16(aQ[0], kr10, S1, 0, 0, 0);
    S1 = __builtin_amdgcn_mfma_f32_16x16x32_bf16(aQ[1], kr11, S1, 0, 0, 0);
    __builtin_amdgcn_s_setprio(0);
    f32x4 Scur[2] = { S0, S1 };

    if (jt < t_lo) {
      #pragma unroll
      for (int ct = 0; ct < 2; ct++) {
        #pragma unroll
        for (int r = 0; r < 4; r++) {
          u32 sg = pkc[ct*4 + r];
          float rw = __uint_as_float(sg & 0xffff0000u);
          float tb = __int_as_float(__builtin_amdgcn_ds_bpermute(
              (int)((sg & 63u) << 2), __float_as_int(treev)));
          float qm = (sg & 128u) ? -1e30f : qd0[r];
          float p = exp2f(__builtin_fmaf(tb, rw, Scur[ct][r] + qm));
          ts0[r] += p;
          Pl[wv][(quad*4 + r)*40 + ct*16 + l15] = f2bf(p);
        }
      }
    } else if (jt > t_hi) {
      #pragma unroll
      for (int ct = 0; ct < 2; ct++) {
        #pragma unroll
        for (int r = 0; r < 4; r++) {
          u32 sg = pkc[ct*4 + r];
          float rw = __uint_as_float(sg & 0xffff0000u);
          float tb = __int_as_float(__builtin_amdgcn_ds_bpermute(
              (int)((sg & 63u) << 2), __float_as_int(treev)));
          float qm = (sg & 128u) ? -1e30f : qd64[r];
          float p = exp2f(__builtin_fmaf(tb, rw, Scur[ct][r] + qm));
          ts1[r] += p;
          Pl[wv][(quad*4 + r)*40 + ct*16 + l15] = f2bf(p);
        }
      }
    } else {
      #pragma unroll
      for (int ct = 0; ct < 2; ct++) {
        #pragma unroll
        for (int r = 0; r < 4; r++) {
          int kloc = ct*16 + l15, qloc = quad*4 + r;
          int d = (k0 + kloc) - (q0 + qloc);
          int bucket = min(max(d + 32, 0), 64);
          u32 sg = pkc[ct*4 + r];
          float rw = __uint_as_float(sg & 0xffff0000u);
          float tb = __int_as_float(__builtin_amdgcn_ds_bpermute(
              (int)((sg & 63u) << 2), __float_as_int(treev)));
          float qd = bf2f(qdotL[(wv*16 + qloc)*68 + bucket]);
          float qm = (sg & 128u) ? -1e30f : qd;
          float p = exp2f(__builtin_fmaf(tb, rw, Scur[ct][r] + qm));
          if (d <= -32)      ts0[r] += p;
          else if (d >= 32)  ts1[r] += p;
          else             { rs[r] += p; PB[wv][qloc*96 + d + 32] = f2bf(p); }
          Pl[wv][qloc*40 + kloc] = f2bf(p);
        }
      }
    }

    {
      short8 aP = *(const short8*)&Pl[wv][l15*40 + quad*8];
      __builtin_amdgcn_s_setprio(1);
      #pragma unroll
      for (int t = 0; t < 4; t++)
        O[t] = __builtin_amdgcn_mfma_f32_16x16x32_bf16(aP, vr[t], O[t], 0, 0, 0);
      __builtin_amdgcn_s_setprio(0);
    }
  }
#undef STAGE

  #pragma unroll
  for (int m = 1; m < 16; m <<= 1) {
    #pragma unroll
    for (int r = 0; r < 4; r++) {
      rs[r]  += __shfl_xor(rs[r],  m, 64);
      ts0[r] += __shfl_xor(ts0[r], m, 64);
      ts1[r] += __shfl_xor(ts1[r], m, 64);
    }
  }
  if (l15 == 0) {
    #pragma unroll
    for (int r = 0; r < 4; r++) {
      PB[wv][(quad*4 + r)*96 + 0]  = f2bf(ts0[r]);
      PB[wv][(quad*4 + r)*96 + 64] = f2bf(ts1[r]);
    }
  }
  // PB is per-wave: ds_write -> ds_read within the same wave, no barrier.

  {
    short8 aB[3];
    #pragma unroll
    for (int s = 0; s < 3; s++)
      aB[s] = *(const short8*)&PB[wv][l15*96 + s*32 + quad*8];
    #pragma unroll
    for (int t = 0; t < 4; t++)
      #pragma unroll
      for (int s = 0; s < 3; s++) {
        short8 bRV = *(const short8*)(relvT + (t*16 + l15)*96 + s*32 + quad*8);
        O[t] = __builtin_amdgcn_mfma_f32_16x16x32_bf16(aB[s], bRV, O[t], 0, 0, 0);
      }
  }

  {
    float inv[4];
    #pragma unroll
    for (int r = 0; r < 4; r++) inv[r] = 1.0f / (rs[r] + ts0[r] + ts1[r]);
    #pragma unroll
    for (int t = 0; t < 4; t++)
      #pragma unroll
      for (int r = 0; r < 4; r++) {
        int qg = q0 + quad*4 + r;
        ctx[(b*1024 + qg)*512 + h*64 + t*16 + l15] = f2bf(O[t][r] * inv[r]);
      }
  }
}

extern "C" void kernel_launch(void* const* d_in, const int* in_sizes, int n_in,
                              void* d_out, int out_size, void* d_ws, size_t ws_size,
                              hipStream_t stream) {
  const float* key   = (const float*)d_in[0];
  const float* value = (const float*)d_in[1];
  const float* query = (const float*)d_in[2];
  const unsigned char* maskp = (const unsigned char*)d_in[3];
  const int*   relm  = (const int*)d_in[4];
  const float* relw  = (const float*)d_in[5];
  const float* Wk = (const float*)d_in[6];
  const float* bk = (const float*)d_in[7];
  const float* Wq = (const float*)d_in[8];
  const float* bq = (const float*)d_in[9];
  const float* Wv = (const float*)d_in[10];
  const float* bv = (const float*)d_in[11];
  const float* Wo = (const float*)d_in[12];
  const float* bo = (const float*)d_in[13];
  const float* rek = (const float*)d_in[14];
  const float* rev = (const float*)d_in[15];
  const float* te  = (const float*)d_in[16];
  (void)in_sizes; (void)n_in; (void)out_size;

  char* w = (char*)d_ws;
  size_t off = 0;
  auto alloc = [&](size_t bytes) -> void* {
    void* p = w + off; off += (bytes + 255) & ~(size_t)255; return p;
  };
  u16* WkT = (u16*)alloc((size_t)512*512*2);
  u16* WqT = (u16*)alloc((size_t)512*512*2);
  u16* WvT = (u16*)alloc((size_t)512*512*2);
  u16* WoT = (u16*)alloc((size_t)512*512*2);
  u16* qws = (u16*)alloc((size_t)8*8*1024*64*2);   // [B,H,L,64], pre-scaled 0.125*log2e
  u16* kws = (u16*)alloc((size_t)8*8*1024*64*2);   // [B,H,L,64]
  u16* vt  = (u16*)alloc((size_t)8*8*1024*64*2);   // [B,H,64,L]
  // 32MB region: first xq/xk/xv (bf16 inputs), later overwritten by packed —
  // safe: stream is serial; QKV gemms consume x* before k_pack writes.
  char* shared32 = (char*)alloc((size_t)8*1024*1024*4);
  u16* xq = (u16*)shared32;
  u16* xk = (u16*)(shared32 + (size_t)8192*512*2);
  u16* xv = (u16*)(shared32 + (size_t)2*8192*512*2);
  u32* packed = (u32*)shared32;
  u16* ctxb = (u16*)alloc((size_t)8192*512*2);     // [B,L,512] bf16
  u16* relk80 = (u16*)alloc((size_t)80*64*2);
  u16* relvT  = (u16*)alloc((size_t)64*96*2);
  if (off > ws_size) return;

  k_wt4<<<dim3(16,16,4), 256, 0, stream>>>(Wk, Wq, Wv, Wo, WkT, WqT, WvT, WoT);
  k_prep_rel<<<44, 256, 0, stream>>>(rek, rev, relk80, relvT);
  k_cvt3<<<dim3(4096,3), 256, 0, stream>>>(query, key, value, xq, xk, xv);

  // Q pre-scaled by 0.125 * log2(e): softmax computed in exp2 domain.
  GArg aq { xq, WqT, bq, (void*)qws, 1, 0.18033688f };
  GArg ak { xk, WkT, bk, (void*)kws, 1, 1.0f };
  GArg av { xv, WvT, bv, (void*)vt,  2, 1.0f };
  k_gemm<<<dim3(8,64,3), 256, 0, stream>>>(aq, ak, av);

  k_pack<<<8192, 256, 0, stream>>>(relm, relw, maskp, packed);

  k_attn<<<dim3(8,8,8), 512, 0, stream>>>(qws, kws, vt, relk80, relvT, te, packed, ctxb);

  GArg ao { ctxb, WoT, bo, d_out, 0, 1.0f };
  k_gemm<<<dim3(8,64,1), 256, 0, stream>>>(ao, ao, ao);
}

// Round 7
// 288.831 us; speedup vs baseline: 1.4102x; 1.1083x over previous
//
#include <hip/hip_runtime.h>
#include <stdint.h>

using f32x4  = __attribute__((ext_vector_type(4))) float;
using short8 = __attribute__((ext_vector_type(8))) short;
typedef unsigned short u16;
typedef unsigned int   u32;

// B=8, H=8, L=1024, DM=512, DK=DV=64.  M = B*L = 8192.

static __device__ __forceinline__ u16 f2bf(float f) {
  union { float f; u32 u; } v; v.f = f;
  u32 r = v.u + 0x7fffu + ((v.u >> 16) & 1u);   // RNE
  return (u16)(r >> 16);
}
static __device__ __forceinline__ float bf2f(u16 u) {
  union { u32 u; float f; } v; v.u = ((u32)u) << 16;
  return v.f;
}
static __device__ __forceinline__ float fexp2(float x) {
  float r;
  asm("v_exp_f32 %0, %1" : "=v"(r) : "v"(x));
  return r;
}
static __device__ __forceinline__ u32 cvtpk(float a, float b) {
  u32 r;
  asm("v_cvt_pk_bf16_f32 %0, %1, %2" : "=v"(r) : "v"(a), "v"(b));
  return r;
}

// async global->LDS, 16B per lane; LDS dest = wave-uniform base + lane*16
#define GLDS16(g, l) __builtin_amdgcn_global_load_lds( \
    (const __attribute__((address_space(1))) u32*)(g), \
    (__attribute__((address_space(3))) u32*)(l), 16, 0, 0)

// ---------------- fused preprocessing: 4 launches -> 1 ----------------
// blocks [0,1024): weight transposes W[512k][512n] -> Wt[n][k] bf16 (4 mats)
// blocks [1024,1068): rel embeddings relk80/relvT
// blocks [1068,13356): f32->bf16 cvt of q/k/v
// blocks [13356,21548): pack rel_matrix|mask|bf16(rel_mask)
__global__ __launch_bounds__(256) void k_pre(
    const float* __restrict__ W0, const float* __restrict__ W1,
    const float* __restrict__ W2, const float* __restrict__ W3,
    u16* __restrict__ T0, u16* __restrict__ T1, u16* __restrict__ T2, u16* __restrict__ T3,
    const float* __restrict__ rk, const float* __restrict__ rv,
    u16* __restrict__ relk80, u16* __restrict__ relvT,
    const float* __restrict__ q, const float* __restrict__ k, const float* __restrict__ v,
    u16* __restrict__ xq, u16* __restrict__ xk, u16* __restrict__ xv,
    const int* __restrict__ rm, const float* __restrict__ rw,
    const unsigned char* __restrict__ mk, u32* __restrict__ outp) {
  __shared__ float t[32][33];
  int bid = blockIdx.x, tid = threadIdx.x;
  if (bid < 1024) {
    int mat = bid >> 8, rem = bid & 255;
    const float* W = (mat == 0) ? W0 : (mat == 1) ? W1 : (mat == 2) ? W2 : W3;
    u16* T = (mat == 0) ? T0 : (mat == 1) ? T1 : (mat == 2) ? T2 : T3;
    int tx = tid & 31, ty = tid >> 5;
    int x0 = (rem & 15) * 32, y0 = (rem >> 4) * 32;
    #pragma unroll
    for (int i = 0; i < 4; i++)
      t[ty + i*8][tx] = W[(y0 + ty + i*8) * 512 + (x0 + tx)];
    __syncthreads();
    #pragma unroll
    for (int i = 0; i < 4; i++)
      T[(x0 + ty + i*8) * 512 + (y0 + tx)] = f2bf(t[tx][ty + i*8]);
  } else if (bid < 1068) {
    int i = (bid - 1024) * 256 + tid;
    if (i < 80*64) {
      int row = i >> 6;
      relk80[i] = (row < 65) ? f2bf(rk[i]) : (u16)0;
    }
    int j = i - 80*64;
    if (j >= 0 && j < 64*96) {
      int dv = j / 96, bk = j % 96;
      relvT[j] = (bk < 65) ? f2bf(rv[bk*64 + dv]) : (u16)0;
    }
  } else if (bid < 13356) {
    int r = bid - 1068;
    int z = r >> 12;
    const float* src = (z == 0) ? q : (z == 1) ? k : v;
    u16* dst = (z == 0) ? xq : (z == 1) ? xk : xv;
    int i = (r & 4095) * 256 + tid;
    float4 f = ((const float4*)src)[i];
    ushort4 o;
    o.x = f2bf(f.x); o.y = f2bf(f.y); o.z = f2bf(f.z); o.w = f2bf(f.w);
    ((ushort4*)dst)[i] = o;
  } else {
    int i = (bid - 13356) * 256 + tid;     // x4 elements
    int4   r4 = ((const int4*)rm)[i];
    float4 w4 = ((const float4*)rw)[i];
    uchar4 m4 = ((const uchar4*)mk)[i];
    uint4 o;
    o.x = (u32)(r4.x & 63) | (m4.x ? 128u : 0u) | ((u32)f2bf(w4.x) << 16);
    o.y = (u32)(r4.y & 63) | (m4.y ? 128u : 0u) | ((u32)f2bf(w4.y) << 16);
    o.z = (u32)(r4.z & 63) | (m4.z ? 128u : 0u) | ((u32)f2bf(w4.z) << 16);
    o.w = (u32)(r4.w & 63) | (m4.w ? 128u : 0u) | ((u32)f2bf(w4.w) << 16);
    ((uint4*)outp)[i] = o;
  }
}

// ---------------- bf16 MFMA GEMM: C = A[8192,512] @ Wt^T + bias -----------
// R12: m97-structure 128x128 tile (was 128x64): 4 waves, acc[4][4], 16 MFMA
// per wave per BK=32 step -> 2x MFMA per barrier. grid (4,64,z).
// mode 0: fp32 out [m][n]; mode 1: bf16 [b,h,l,d]; mode 2: bf16 [b,h,d,l]
// (N-tile now spans 2 heads).
struct GArg { const u16* A; const u16* Wt; const float* bias; void* out; int mode; float scale; };

__global__ __launch_bounds__(256, 3) void k_gemm(GArg g0, GArg g1, GArg g2) {
  GArg ar = (blockIdx.z == 0) ? g0 : (blockIdx.z == 1) ? g1 : g2;
  __shared__ u16 As[128*32];   // chunk c (16B) at byte c*16: row=c>>2, slot=c&3
  __shared__ u16 Bs[128*32];
  __shared__ u16 Cs[128*136];  // epilogue staging, stride 136
  int tid = threadIdx.x, lane = tid & 63, wv = tid >> 6;
  int quad = lane >> 4, l15 = lane & 15;
  int n0 = blockIdx.x * 128, m0 = blockIdx.y * 128;
  int wm = (wv >> 1) * 64, wn = (wv & 1) * 64;
  f32x4 acc[4][4];
  #pragma unroll
  for (int i = 0; i < 4; i++)
    #pragma unroll
    for (int j = 0; j < 4; j++)
      acc[i][j] = (f32x4){0.f, 0.f, 0.f, 0.f};

  const u16* Abase = ar.A  + (size_t)m0 * 512;
  const u16* Bbase = ar.Wt + (size_t)n0 * 512;
  int c0 = wv * 128;                      // wave-uniform chunk base (512 chunks)

  for (int k0 = 0; k0 < 512; k0 += 32) {
    #pragma unroll
    for (int i = 0; i < 2; i++) {
      int c = c0 + i*64 + lane;
      GLDS16(Abase + (c >> 2)*512 + k0 + (c & 3)*8, &As[(c0 + i*64)*8]);
      GLDS16(Bbase + (c >> 2)*512 + k0 + (c & 3)*8, &Bs[(c0 + i*64)*8]);
    }
    __syncthreads();
    short8 af[4], bf[4];
    #pragma unroll
    for (int i = 0; i < 4; i++) af[i] = *(const short8*)&As[(wm + i*16 + l15)*32 + quad*8];
    #pragma unroll
    for (int j = 0; j < 4; j++) bf[j] = *(const short8*)&Bs[(wn + j*16 + l15)*32 + quad*8];
    #pragma unroll
    for (int i = 0; i < 4; i++)
      #pragma unroll
      for (int j = 0; j < 4; j++)
        acc[i][j] = __builtin_amdgcn_mfma_f32_16x16x32_bf16(af[i], bf[j], acc[i][j], 0, 0, 0);
    __syncthreads();
  }

  if (ar.mode == 0) {
    #pragma unroll
    for (int i = 0; i < 4; i++)
      #pragma unroll
      for (int j = 0; j < 4; j++) {
        int ncol = n0 + wn + j*16 + l15;
        float bv = ar.bias[ncol];
        #pragma unroll
        for (int r = 0; r < 4; r++) {
          int m = m0 + wm + i*16 + quad*4 + r;
          ((float*)ar.out)[m*512 + ncol] = (acc[i][j][r] + bv) * ar.scale;
        }
      }
  } else {
    #pragma unroll
    for (int i = 0; i < 4; i++)
      #pragma unroll
      for (int j = 0; j < 4; j++) {
        int nloc = wn + j*16 + l15;
        float bv = ar.bias[n0 + nloc];
        #pragma unroll
        for (int r = 0; r < 4; r++) {
          int mloc = wm + i*16 + quad*4 + r;
          float val = (acc[i][j][r] + bv) * ar.scale;
          if (ar.mode == 1) Cs[mloc*136 + nloc] = f2bf(val);
          else              Cs[nloc*136 + mloc] = f2bf(val);
        }
      }
    __syncthreads();
    int bb = m0 >> 10, hh0 = n0 >> 6, mbase = m0 & 1023;
    u16* outp = (u16*)ar.out;
    if (ar.mode == 1) {
      // [b,h,l,d]: rows 128, 2 heads x 64 d
      #pragma unroll
      for (int p = 0; p < 8; p++) {
        int mloc = (tid >> 4) + p*16, seg = tid & 15;
        int head = hh0 + (seg >> 3);
        size_t base = ((size_t)(bb*8 + head)*1024 + mbase)*64;
        *(short8*)(outp + base + (size_t)mloc*64 + (seg & 7)*8) =
            *(const short8*)&Cs[mloc*136 + seg*8];
      }
    } else {
      // [b,h,d,l]: 128 n-rows = 2 heads x 64 d, 128 m contiguous each
      #pragma unroll
      for (int p = 0; p < 8; p++) {
        int nloc = (tid >> 4) + p*16, seg = tid & 15;
        int head = hh0 + (nloc >> 6), d = nloc & 63;
        size_t base = (size_t)(bb*8 + head)*64*1024 + mbase;
        *(short8*)(outp + base + (size_t)d*1024 + seg*8) =
            *(const short8*)&Cs[nloc*136 + seg*8];
      }
    }
  }
}

// ---------------- fused attention ----------------
// R12 (on top of R11 8-wave structure): VALU diet in the hot loop.
//  - exp2f (libm, ~6 inst) -> raw v_exp_f32 asm (1 inst).
//  - Pl bf16 stores: v_cvt_pk_bf16_f32 pairs (1 inst / 2 conversions, RNE
//    same as f2bf) + (u16)(x>>16) stores that select ds_write_b16_d16_hi.
__global__ __launch_bounds__(512, 4) void k_attn(
    const u16* __restrict__ qws, const u16* __restrict__ kws, const u16* __restrict__ vtws,
    const u16* __restrict__ relk80, const u16* __restrict__ relvT,
    const float* __restrict__ tree_emb, const u32* __restrict__ packed,
    u16* __restrict__ ctx) {
  __shared__ u16 Kb[2][2048];       // [buf][32 k-rows][64 d] swizzled
  __shared__ u16 Vb[2][2048];       // [buf][64 d-rows][32 k] swizzled
  __shared__ u16 qdotL[8*16*68];    // [w][q][bucket]  (band tiles)
  __shared__ u16 PB[8][16*96];      // per-wave banded P
  __shared__ u16 Pl[8][16*40];      // per-wave C->A bridge, stride 40

  int tid = threadIdx.x, lane = tid & 63, wv = tid >> 6;
  int quad = lane >> 4, l15 = lane & 15;
  int qb = blockIdx.x, h = blockIdx.y, b = blockIdx.z;
  int q0 = qb * 128 + wv * 16;

  // register tree table: lane v (0..63) holds tree_emb[v][h] * log2e
  float treev = tree_emb[lane * 8 + h] * 1.44269504f;

  #pragma unroll
  for (int i = 0; i < 12; i++) ((u32*)&PB[wv][0])[lane + i*64] = 0u;

  const u16* qp = qws  + (size_t)(b*8 + h)*(1024*64);
  const u16* kp = kws  + (size_t)(b*8 + h)*(1024*64);
  const u16* vp = vtws + (size_t)(b*8 + h)*(64*1024);
  const u32* pkb = packed + ((size_t)b << 20);

  // staging roles: waves 0-3 carry K rows; waves 4-7 carry V rows.
  int rk = (wv & 3)*8 + (lane >> 3);
  int swk = (((lane & 7)*8) ^ ((rk & 7) << 3));
  int rv = (wv & 3)*16 + (lane >> 2);
  const u16* vsrc = vp + (size_t)rv*1024 + (((lane & 3)*8) ^ ((rv & 3) << 3));

#define STAGE(kt, nb) do { \
    if (wv < 4) GLDS16(kp + (size_t)((kt)*32 + rk)*64 + swk, &Kb[nb][wv*512]); \
    else        GLDS16(vsrc + (kt)*32, &Vb[nb][(wv & 3)*512]); \
  } while (0)

  STAGE(0, 0);

  short8 aQ[2];
  #pragma unroll
  for (int kf = 0; kf < 2; kf++)
    aQ[kf] = *(const short8*)(qp + (q0 + l15)*64 + kf*32 + quad*8);

  float qd0[4], qd64[4];
  #pragma unroll
  for (int t = 0; t < 5; t++) {
    f32x4 C = (f32x4){0.f,0.f,0.f,0.f};
    #pragma unroll
    for (int kf = 0; kf < 2; kf++) {
      short8 bR = *(const short8*)(relk80 + (t*16 + l15)*64 + kf*32 + quad*8);
      C = __builtin_amdgcn_mfma_f32_16x16x32_bf16(aQ[kf], bR, C, 0, 0, 0);
    }
    if (t == 0) {
      #pragma unroll
      for (int r = 0; r < 4; r++) qd0[r] = __shfl(C[r], lane & 48, 64);
    }
    if (t == 4) {
      #pragma unroll
      for (int r = 0; r < 4; r++) qd64[r] = __shfl(C[r], lane & 48, 64);
    }
    int col = t*16 + l15;
    if (col < 65) {
      #pragma unroll
      for (int r = 0; r < 4; r++)
        qdotL[(wv*16 + quad*4 + r)*68 + col] = f2bf(C[r]);
    }
  }

  int t_lo = max(0, (q0 - 31) >> 5);
  int t_hi = min(31, (q0 + 46) >> 5);

  // precomputed LDS read offsets (u16 units); ct adds 1024, t adds 512
  int sK = (l15 & 7) << 3;
  int kbo0 = l15*64 + ((quad*8) ^ sK);          // kf=0
  int kbo1 = l15*64 + (((4 + quad)*8) ^ sK);    // kf=1
  int vbo  = l15*32 + ((quad*8) ^ ((l15 & 3) << 3));

  u32 pk[8];
  #pragma unroll
  for (int e = 0; e < 8; e++)
    pk[e] = pkb[((q0 + quad*4 + (e & 3)) << 10) + (e >> 2)*16 + l15];

  f32x4 O[4];
  float rs[4], ts0[4], ts1[4];
  #pragma unroll
  for (int t = 0; t < 4; t++) O[t] = (f32x4){0.f,0.f,0.f,0.f};
  #pragma unroll
  for (int r = 0; r < 4; r++) { rs[r] = 0.f; ts0[r] = 0.f; ts1[r] = 0.f; }

  for (int jt = 0; jt < 32; ++jt) {
    int cur = jt & 1;
    int k0 = jt << 5;
    __syncthreads();                    // stage(jt) complete; readers of buf cur^1 done
    if (jt < 31) STAGE(jt + 1, cur ^ 1);

    u32 pkc[8];
    #pragma unroll
    for (int e = 0; e < 8; e++) pkc[e] = pk[e];
    if (jt < 31) {
      int kn = (jt + 1) << 5;
      #pragma unroll
      for (int e = 0; e < 8; e++)
        pk[e] = pkb[((q0 + quad*4 + (e & 3)) << 10) + kn + (e >> 2)*16 + l15];
    }

    short8 kr00 = *(const short8*)&Kb[cur][kbo0];
    short8 kr01 = *(const short8*)&Kb[cur][kbo1];
    short8 kr10 = *(const short8*)&Kb[cur][1024 + kbo0];
    short8 kr11 = *(const short8*)&Kb[cur][1024 + kbo1];
    short8 vr[4];
    #pragma unroll
    for (int t = 0; t < 4; t++) vr[t] = *(const short8*)&Vb[cur][t*512 + vbo];

    f32x4 S0 = (f32x4){0.f,0.f,0.f,0.f}, S1 = (f32x4){0.f,0.f,0.f,0.f};
    __builtin_amdgcn_s_setprio(1);
    S0 = __builtin_amdgcn_mfma_f32_16x16x32_bf16(aQ[0], kr00, S0, 0, 0, 0);
    S0 = __builtin_amdgcn_mfma_f32_16x16x32_bf16(aQ[1], kr01, S0, 0, 0, 0);
    S1 = __builtin_amdgcn_mfma_f32_16x16x32_bf16(aQ[0], kr10, S1, 0, 0, 0);
    S1 = __builtin_amdgcn_mfma_f32_16x16x32_bf16(aQ[1], kr11, S1, 0, 0, 0);
    __builtin_amdgcn_s_setprio(0);
    f32x4 Scur[2] = { S0, S1 };

    if (jt < t_lo) {
      #pragma unroll
      for (int ct = 0; ct < 2; ct++) {
        float pv[4];
        #pragma unroll
        for (int r = 0; r < 4; r++) {
          u32 sg = pkc[ct*4 + r];
          float rw = __uint_as_float(sg & 0xffff0000u);
          float tb = __int_as_float(__builtin_amdgcn_ds_bpermute(
              (int)((sg & 63u) << 2), __float_as_int(treev)));
          float qm = (sg & 128u) ? -1e30f : qd0[r];
          float p = fexp2(__builtin_fmaf(tb, rw, Scur[ct][r] + qm));
          ts0[r] += p;
          pv[r] = p;
        }
        u32 c01 = cvtpk(pv[0], pv[1]), c23 = cvtpk(pv[2], pv[3]);
        u16* pl = &Pl[wv][(quad*4)*40 + ct*16 + l15];
        pl[0]   = (u16)c01; pl[40]  = (u16)(c01 >> 16);
        pl[80]  = (u16)c23; pl[120] = (u16)(c23 >> 16);
      }
    } else if (jt > t_hi) {
      #pragma unroll
      for (int ct = 0; ct < 2; ct++) {
        float pv[4];
        #pragma unroll
        for (int r = 0; r < 4; r++) {
          u32 sg = pkc[ct*4 + r];
          float rw = __uint_as_float(sg & 0xffff0000u);
          float tb = __int_as_float(__builtin_amdgcn_ds_bpermute(
              (int)((sg & 63u) << 2), __float_as_int(treev)));
          float qm = (sg & 128u) ? -1e30f : qd64[r];
          float p = fexp2(__builtin_fmaf(tb, rw, Scur[ct][r] + qm));
          ts1[r] += p;
          pv[r] = p;
        }
        u32 c01 = cvtpk(pv[0], pv[1]), c23 = cvtpk(pv[2], pv[3]);
        u16* pl = &Pl[wv][(quad*4)*40 + ct*16 + l15];
        pl[0]   = (u16)c01; pl[40]  = (u16)(c01 >> 16);
        pl[80]  = (u16)c23; pl[120] = (u16)(c23 >> 16);
      }
    } else {
      #pragma unroll
      for (int ct = 0; ct < 2; ct++) {
        float pv[4];
        #pragma unroll
        for (int r = 0; r < 4; r++) {
          int kloc = ct*16 + l15, qloc = quad*4 + r;
          int d = (k0 + kloc) - (q0 + qloc);
          int bucket = min(max(d + 32, 0), 64);
          u32 sg = pkc[ct*4 + r];
          float rw = __uint_as_float(sg & 0xffff0000u);
          float tb = __int_as_float(__builtin_amdgcn_ds_bpermute(
              (int)((sg & 63u) << 2), __float_as_int(treev)));
          float qd = bf2f(qdotL[(wv*16 + qloc)*68 + bucket]);
          float qm = (sg & 128u) ? -1e30f : qd;
          float p = fexp2(__builtin_fmaf(tb, rw, Scur[ct][r] + qm));
          if (d <= -32)      ts0[r] += p;
          else if (d >= 32)  ts1[r] += p;
          else             { rs[r] += p; PB[wv][qloc*96 + d + 32] = f2bf(p); }
          pv[r] = p;
        }
        u32 c01 = cvtpk(pv[0], pv[1]), c23 = cvtpk(pv[2], pv[3]);
        u16* pl = &Pl[wv][(quad*4)*40 + ct*16 + l15];
        pl[0]   = (u16)c01; pl[40]  = (u16)(c01 >> 16);
        pl[80]  = (u16)c23; pl[120] = (u16)(c23 >> 16);
      }
    }

    {
      short8 aP = *(const short8*)&Pl[wv][l15*40 + quad*8];
      __builtin_amdgcn_s_setprio(1);
      #pragma unroll
      for (int t = 0; t < 4; t++)
        O[t] = __builtin_amdgcn_mfma_f32_16x16x32_bf16(aP, vr[t], O[t], 0, 0, 0);
      __builtin_amdgcn_s_setprio(0);
    }
  }
#undef STAGE

  #pragma unroll
  for (int m = 1; m < 16; m <<= 1) {
    #pragma unroll
    for (int r = 0; r < 4; r++) {
      rs[r]  += __shfl_xor(rs[r],  m, 64);
      ts0[r] += __shfl_xor(ts0[r], m, 64);
      ts1[r] += __shfl_xor(ts1[r], m, 64);
    }
  }
  if (l15 == 0) {
    #pragma unroll
    for (int r = 0; r < 4; r++) {
      PB[wv][(quad*4 + r)*96 + 0]  = f2bf(ts0[r]);
      PB[wv][(quad*4 + r)*96 + 64] = f2bf(ts1[r]);
    }
  }
  // PB is per-wave: ds_write -> ds_read within the same wave, no barrier.

  {
    short8 aB[3];
    #pragma unroll
    for (int s = 0; s < 3; s++)
      aB[s] = *(const short8*)&PB[wv][l15*96 + s*32 + quad*8];
    #pragma unroll
    for (int t = 0; t < 4; t++)
      #pragma unroll
      for (int s = 0; s < 3; s++) {
        short8 bRV = *(const short8*)(relvT + (t*16 + l15)*96 + s*32 + quad*8);
        O[t] = __builtin_amdgcn_mfma_f32_16x16x32_bf16(aB[s], bRV, O[t], 0, 0, 0);
      }
  }

  {
    float inv[4];
    #pragma unroll
    for (int r = 0; r < 4; r++) inv[r] = 1.0f / (rs[r] + ts0[r] + ts1[r]);
    #pragma unroll
    for (int t = 0; t < 4; t++)
      #pragma unroll
      for (int r = 0; r < 4; r++) {
        int qg = q0 + quad*4 + r;
        ctx[(b*1024 + qg)*512 + h*64 + t*16 + l15] = f2bf(O[t][r] * inv[r]);
      }
  }
}

extern "C" void kernel_launch(void* const* d_in, const int* in_sizes, int n_in,
                              void* d_out, int out_size, void* d_ws, size_t ws_size,
                              hipStream_t stream) {
  const float* key   = (const float*)d_in[0];
  const float* value = (const float*)d_in[1];
  const float* query = (const float*)d_in[2];
  const unsigned char* maskp = (const unsigned char*)d_in[3];
  const int*   relm  = (const int*)d_in[4];
  const float* relw  = (const float*)d_in[5];
  const float* Wk = (const float*)d_in[6];
  const float* bk = (const float*)d_in[7];
  const float* Wq = (const float*)d_in[8];
  const float* bq = (const float*)d_in[9];
  const float* Wv = (const float*)d_in[10];
  const float* bv = (const float*)d_in[11];
  const float* Wo = (const float*)d_in[12];
  const float* bo = (const float*)d_in[13];
  const float* rek = (const float*)d_in[14];
  const float* rev = (const float*)d_in[15];
  const float* te  = (const float*)d_in[16];
  (void)in_sizes; (void)n_in; (void)out_size;

  char* w = (char*)d_ws;
  size_t off = 0;
  auto alloc = [&](size_t bytes) -> void* {
    void* p = w + off; off += (bytes + 255) & ~(size_t)255; return p;
  };
  u16* WkT = (u16*)alloc((size_t)512*512*2);
  u16* WqT = (u16*)alloc((size_t)512*512*2);
  u16* WvT = (u16*)alloc((size_t)512*512*2);
  u16* WoT = (u16*)alloc((size_t)512*512*2);
  u16* qws = (u16*)alloc((size_t)8*8*1024*64*2);   // [B,H,L,64], pre-scaled 0.125*log2e
  u16* kws = (u16*)alloc((size_t)8*8*1024*64*2);   // [B,H,L,64]
  u16* vt  = (u16*)alloc((size_t)8*8*1024*64*2);   // [B,H,64,L]
  u16* xq  = (u16*)alloc((size_t)8192*512*2);
  u16* xk  = (u16*)alloc((size_t)8192*512*2);
  u16* xv  = (u16*)alloc((size_t)8192*512*2);
  u32* packed = (u32*)alloc((size_t)8*1024*1024*4);
  u16* ctxb = (u16*)alloc((size_t)8192*512*2);     // [B,L,512] bf16
  u16* relk80 = (u16*)alloc((size_t)80*64*2);
  u16* relvT  = (u16*)alloc((size_t)64*96*2);
  if (off > ws_size) return;

  k_pre<<<21548, 256, 0, stream>>>(Wk, Wq, Wv, Wo, WkT, WqT, WvT, WoT,
                                   rek, rev, relk80, relvT,
                                   query, key, value, xq, xk, xv,
                                   relm, relw, maskp, packed);

  // Q pre-scaled by 0.125 * log2(e): softmax computed in exp2 domain.
  GArg aq { xq, WqT, bq, (void*)qws, 1, 0.18033688f };
  GArg ak { xk, WkT, bk, (void*)kws, 1, 1.0f };
  GArg av { xv, WvT, bv, (void*)vt,  2, 1.0f };
  k_gemm<<<dim3(4,64,3), 256, 0, stream>>>(aq, ak, av);

  k_attn<<<dim3(8,8,8), 512, 0, stream>>>(qws, kws, vt, relk80, relvT, te, packed, ctxb);

  GArg ao { ctxb, WoT, bo, d_out, 0, 1.0f };
  k_gemm<<<dim3(4,64,1), 256, 0, stream>>>(ao, ao, ao);
}

// Round 8
// 287.849 us; speedup vs baseline: 1.4150x; 1.0034x over previous
//
#include <hip/hip_runtime.h>
#include <stdint.h>

using f32x4  = __attribute__((ext_vector_type(4))) float;
using short8 = __attribute__((ext_vector_type(8))) short;
typedef unsigned short u16;
typedef unsigned int   u32;

// B=8, H=8, L=1024, DM=512, DK=DV=64.  M = B*L = 8192.

static __device__ __forceinline__ u16 f2bf(float f) {
  union { float f; u32 u; } v; v.f = f;
  u32 r = v.u + 0x7fffu + ((v.u >> 16) & 1u);   // RNE
  return (u16)(r >> 16);
}
static __device__ __forceinline__ float bf2f(u16 u) {
  union { u32 u; float f; } v; v.u = ((u32)u) << 16;
  return v.f;
}
static __device__ __forceinline__ float fexp2(float x) {
  float r;
  asm("v_exp_f32 %0, %1" : "=v"(r) : "v"(x));
  return r;
}
static __device__ __forceinline__ u32 cvtpk(float a, float b) {
  u32 r;
  asm("v_cvt_pk_bf16_f32 %0, %1, %2" : "=v"(r) : "v"(a), "v"(b));
  return r;
}

// async global->LDS, 16B per lane; LDS dest = wave-uniform base + lane*16
#define GLDS16(g, l) __builtin_amdgcn_global_load_lds( \
    (const __attribute__((address_space(1))) u32*)(g), \
    (__attribute__((address_space(3))) u32*)(l), 16, 0, 0)

// ---------------- fused preprocessing: 4 launches -> 1 ----------------
__global__ __launch_bounds__(256) void k_pre(
    const float* __restrict__ W0, const float* __restrict__ W1,
    const float* __restrict__ W2, const float* __restrict__ W3,
    u16* __restrict__ T0, u16* __restrict__ T1, u16* __restrict__ T2, u16* __restrict__ T3,
    const float* __restrict__ rk, const float* __restrict__ rv,
    u16* __restrict__ relk80, u16* __restrict__ relvT,
    const float* __restrict__ q, const float* __restrict__ k, const float* __restrict__ v,
    u16* __restrict__ xq, u16* __restrict__ xk, u16* __restrict__ xv,
    const int* __restrict__ rm, const float* __restrict__ rw,
    const unsigned char* __restrict__ mk, u32* __restrict__ outp) {
  __shared__ float t[32][33];
  int bid = blockIdx.x, tid = threadIdx.x;
  if (bid < 1024) {
    int mat = bid >> 8, rem = bid & 255;
    const float* W = (mat == 0) ? W0 : (mat == 1) ? W1 : (mat == 2) ? W2 : W3;
    u16* T = (mat == 0) ? T0 : (mat == 1) ? T1 : (mat == 2) ? T2 : T3;
    int tx = tid & 31, ty = tid >> 5;
    int x0 = (rem & 15) * 32, y0 = (rem >> 4) * 32;
    #pragma unroll
    for (int i = 0; i < 4; i++)
      t[ty + i*8][tx] = W[(y0 + ty + i*8) * 512 + (x0 + tx)];
    __syncthreads();
    #pragma unroll
    for (int i = 0; i < 4; i++)
      T[(x0 + ty + i*8) * 512 + (y0 + tx)] = f2bf(t[tx][ty + i*8]);
  } else if (bid < 1068) {
    int i = (bid - 1024) * 256 + tid;
    if (i < 80*64) {
      int row = i >> 6;
      relk80[i] = (row < 65) ? f2bf(rk[i]) : (u16)0;
    }
    int j = i - 80*64;
    if (j >= 0 && j < 64*96) {
      int dv = j / 96, bk = j % 96;
      relvT[j] = (bk < 65) ? f2bf(rv[bk*64 + dv]) : (u16)0;
    }
  } else if (bid < 13356) {
    int r = bid - 1068;
    int z = r >> 12;
    const float* src = (z == 0) ? q : (z == 1) ? k : v;
    u16* dst = (z == 0) ? xq : (z == 1) ? xk : xv;
    int i = (r & 4095) * 256 + tid;
    float4 f = ((const float4*)src)[i];
    ushort4 o;
    o.x = f2bf(f.x); o.y = f2bf(f.y); o.z = f2bf(f.z); o.w = f2bf(f.w);
    ((ushort4*)dst)[i] = o;
  } else {
    int i = (bid - 13356) * 256 + tid;     // x4 elements
    int4   r4 = ((const int4*)rm)[i];
    float4 w4 = ((const float4*)rw)[i];
    uchar4 m4 = ((const uchar4*)mk)[i];
    uint4 o;
    o.x = (u32)(r4.x & 63) | (m4.x ? 128u : 0u) | ((u32)f2bf(w4.x) << 16);
    o.y = (u32)(r4.y & 63) | (m4.y ? 128u : 0u) | ((u32)f2bf(w4.y) << 16);
    o.z = (u32)(r4.z & 63) | (m4.z ? 128u : 0u) | ((u32)f2bf(w4.z) << 16);
    o.w = (u32)(r4.w & 63) | (m4.w ? 128u : 0u) | ((u32)f2bf(w4.w) << 16);
    ((uint4*)outp)[i] = o;
  }
}

// ---------------- bf16 MFMA GEMM: C = A[8192,512] @ Wt^T + bias -----------
// R13: double-buffered staging, ONE barrier per K-step (k_attn's proven
// STAGE pattern): stage(k+1) issued right after the barrier, MFMA on buf k
// underneath -- kills the per-step vmcnt(0)+2-barrier drain (16 K-steps
// amortize nothing). Epilogue Cs unioned with staging bufs: LDS 34 KB ->
// 4 blocks/CU under launch_bounds(256,4) (live ~110 VGPR < 128, no spill).
struct GArg { const u16* A; const u16* Wt; const float* bias; void* out; int mode; float scale; };

__global__ __launch_bounds__(256, 4) void k_gemm(GArg g0, GArg g1, GArg g2) {
  GArg ar = (blockIdx.z == 0) ? g0 : (blockIdx.z == 1) ? g1 : g2;
  __shared__ char smem_[34816];
  u16* As = (u16*)smem_;             // [2][4096] u16 (buf*4096)
  u16* Bs = (u16*)(smem_ + 16384);   // [2][4096] u16
  u16* Cs = (u16*)smem_;             // epilogue staging [128][136] (after barrier)
  int tid = threadIdx.x, lane = tid & 63, wv = tid >> 6;
  int quad = lane >> 4, l15 = lane & 15;
  int n0 = blockIdx.x * 128, m0 = blockIdx.y * 128;
  int wm = (wv >> 1) * 64, wn = (wv & 1) * 64;
  f32x4 acc[4][4];
  #pragma unroll
  for (int i = 0; i < 4; i++)
    #pragma unroll
    for (int j = 0; j < 4; j++)
      acc[i][j] = (f32x4){0.f, 0.f, 0.f, 0.f};

  const u16* Abase = ar.A  + (size_t)m0 * 512;
  const u16* Bbase = ar.Wt + (size_t)n0 * 512;
  int c0 = wv * 128;                      // wave-uniform chunk base

#define STAGEG(kt, nb) do { \
    _Pragma("unroll") \
    for (int i = 0; i < 2; i++) { \
      int c = c0 + i*64 + lane; \
      GLDS16(Abase + (c >> 2)*512 + (kt)*32 + (c & 3)*8, &As[(nb)*4096 + (c0 + i*64)*8]); \
      GLDS16(Bbase + (c >> 2)*512 + (kt)*32 + (c & 3)*8, &Bs[(nb)*4096 + (c0 + i*64)*8]); \
    } } while (0)

  STAGEG(0, 0);

  for (int ks = 0; ks < 16; ks++) {
    int cur = ks & 1;
    __syncthreads();                     // stage(ks) landed; buf cur^1 readers done
    if (ks < 15) STAGEG(ks + 1, cur ^ 1);
    int bs = cur * 4096;
    short8 af[4], bf[4];
    #pragma unroll
    for (int i = 0; i < 4; i++) af[i] = *(const short8*)&As[bs + (wm + i*16 + l15)*32 + quad*8];
    #pragma unroll
    for (int j = 0; j < 4; j++) bf[j] = *(const short8*)&Bs[bs + (wn + j*16 + l15)*32 + quad*8];
    __builtin_amdgcn_s_setprio(1);
    #pragma unroll
    for (int i = 0; i < 4; i++)
      #pragma unroll
      for (int j = 0; j < 4; j++)
        acc[i][j] = __builtin_amdgcn_mfma_f32_16x16x32_bf16(af[i], bf[j], acc[i][j], 0, 0, 0);
    __builtin_amdgcn_s_setprio(0);
  }
#undef STAGEG
  __syncthreads();                       // all ds_reads drained before Cs aliases As/Bs

  if (ar.mode == 0) {
    #pragma unroll
    for (int i = 0; i < 4; i++)
      #pragma unroll
      for (int j = 0; j < 4; j++) {
        int ncol = n0 + wn + j*16 + l15;
        float bv = ar.bias[ncol];
        #pragma unroll
        for (int r = 0; r < 4; r++) {
          int m = m0 + wm + i*16 + quad*4 + r;
          ((float*)ar.out)[m*512 + ncol] = (acc[i][j][r] + bv) * ar.scale;
        }
      }
  } else {
    #pragma unroll
    for (int i = 0; i < 4; i++)
      #pragma unroll
      for (int j = 0; j < 4; j++) {
        int nloc = wn + j*16 + l15;
        float bv = ar.bias[n0 + nloc];
        #pragma unroll
        for (int r = 0; r < 4; r++) {
          int mloc = wm + i*16 + quad*4 + r;
          float val = (acc[i][j][r] + bv) * ar.scale;
          if (ar.mode == 1) Cs[mloc*136 + nloc] = f2bf(val);
          else              Cs[nloc*136 + mloc] = f2bf(val);
        }
      }
    __syncthreads();
    int bb = m0 >> 10, hh0 = n0 >> 6, mbase = m0 & 1023;
    u16* outp = (u16*)ar.out;
    if (ar.mode == 1) {
      // [b,h,l,d]: rows 128, 2 heads x 64 d
      #pragma unroll
      for (int p = 0; p < 8; p++) {
        int mloc = (tid >> 4) + p*16, seg = tid & 15;
        int head = hh0 + (seg >> 3);
        size_t base = ((size_t)(bb*8 + head)*1024 + mbase)*64;
        *(short8*)(outp + base + (size_t)mloc*64 + (seg & 7)*8) =
            *(const short8*)&Cs[mloc*136 + seg*8];
      }
    } else {
      // [b,h,d,l]: 128 n-rows = 2 heads x 64 d, 128 m contiguous each
      #pragma unroll
      for (int p = 0; p < 8; p++) {
        int nloc = (tid >> 4) + p*16, seg = tid & 15;
        int head = hh0 + (nloc >> 6), d = nloc & 63;
        size_t base = (size_t)(bb*8 + head)*64*1024 + mbase;
        *(short8*)(outp + base + (size_t)d*1024 + seg*8) =
            *(const short8*)&Cs[nloc*136 + seg*8];
      }
    }
  }
}

// ---------------- fused attention ----------------
// R13: XCD-locality grid order. Old grid (x=qb fastest) put the 8 qb-blocks
// that share one (b,h)'s K/V on 8 DIFFERENT XCDs (round-robin) -> each
// re-staged K/V from HBM (FETCH 86MB vs ~50 ideal). New order d = h + 8b +
// 64qb: d%8 = h, so all blocks of head h land on XCD h; the 8 qb-siblings
// of each (b,h) share that XCD's L2 -> K/V staged from L2 after first touch.
__global__ __launch_bounds__(512, 4) void k_attn(
    const u16* __restrict__ qws, const u16* __restrict__ kws, const u16* __restrict__ vtws,
    const u16* __restrict__ relk80, const u16* __restrict__ relvT,
    const float* __restrict__ tree_emb, const u32* __restrict__ packed,
    u16* __restrict__ ctx) {
  __shared__ u16 Kb[2][2048];       // [buf][32 k-rows][64 d] swizzled
  __shared__ u16 Vb[2][2048];       // [buf][64 d-rows][32 k] swizzled
  __shared__ u16 qdotL[8*16*68];    // [w][q][bucket]  (band tiles)
  __shared__ u16 PB[8][16*96];      // per-wave banded P
  __shared__ u16 Pl[8][16*40];      // per-wave C->A bridge, stride 40

  int tid = threadIdx.x, lane = tid & 63, wv = tid >> 6;
  int quad = lane >> 4, l15 = lane & 15;
  int h = blockIdx.x, b = blockIdx.y, qb = blockIdx.z;   // XCD = h
  int q0 = qb * 128 + wv * 16;

  // register tree table: lane v (0..63) holds tree_emb[v][h] * log2e
  float treev = tree_emb[lane * 8 + h] * 1.44269504f;

  #pragma unroll
  for (int i = 0; i < 12; i++) ((u32*)&PB[wv][0])[lane + i*64] = 0u;

  const u16* qp = qws  + (size_t)(b*8 + h)*(1024*64);
  const u16* kp = kws  + (size_t)(b*8 + h)*(1024*64);
  const u16* vp = vtws + (size_t)(b*8 + h)*(64*1024);
  const u32* pkb = packed + ((size_t)b << 20);

  // staging roles: waves 0-3 carry K rows; waves 4-7 carry V rows.
  int rk = (wv & 3)*8 + (lane >> 3);
  int swk = (((lane & 7)*8) ^ ((rk & 7) << 3));
  int rv = (wv & 3)*16 + (lane >> 2);
  const u16* vsrc = vp + (size_t)rv*1024 + (((lane & 3)*8) ^ ((rv & 3) << 3));

#define STAGE(kt, nb) do { \
    if (wv < 4) GLDS16(kp + (size_t)((kt)*32 + rk)*64 + swk, &Kb[nb][wv*512]); \
    else        GLDS16(vsrc + (kt)*32, &Vb[nb][(wv & 3)*512]); \
  } while (0)

  STAGE(0, 0);

  short8 aQ[2];
  #pragma unroll
  for (int kf = 0; kf < 2; kf++)
    aQ[kf] = *(const short8*)(qp + (q0 + l15)*64 + kf*32 + quad*8);

  float qd0[4], qd64[4];
  #pragma unroll
  for (int t = 0; t < 5; t++) {
    f32x4 C = (f32x4){0.f,0.f,0.f,0.f};
    #pragma unroll
    for (int kf = 0; kf < 2; kf++) {
      short8 bR = *(const short8*)(relk80 + (t*16 + l15)*64 + kf*32 + quad*8);
      C = __builtin_amdgcn_mfma_f32_16x16x32_bf16(aQ[kf], bR, C, 0, 0, 0);
    }
    if (t == 0) {
      #pragma unroll
      for (int r = 0; r < 4; r++) qd0[r] = __shfl(C[r], lane & 48, 64);
    }
    if (t == 4) {
      #pragma unroll
      for (int r = 0; r < 4; r++) qd64[r] = __shfl(C[r], lane & 48, 64);
    }
    int col = t*16 + l15;
    if (col < 65) {
      #pragma unroll
      for (int r = 0; r < 4; r++)
        qdotL[(wv*16 + quad*4 + r)*68 + col] = f2bf(C[r]);
    }
  }

  int t_lo = max(0, (q0 - 31) >> 5);
  int t_hi = min(31, (q0 + 46) >> 5);

  // precomputed LDS read offsets (u16 units); ct adds 1024, t adds 512
  int sK = (l15 & 7) << 3;
  int kbo0 = l15*64 + ((quad*8) ^ sK);          // kf=0
  int kbo1 = l15*64 + (((4 + quad)*8) ^ sK);    // kf=1
  int vbo  = l15*32 + ((quad*8) ^ ((l15 & 3) << 3));

  u32 pk[8];
  #pragma unroll
  for (int e = 0; e < 8; e++)
    pk[e] = pkb[((q0 + quad*4 + (e & 3)) << 10) + (e >> 2)*16 + l15];

  f32x4 O[4];
  float rs[4], ts0[4], ts1[4];
  #pragma unroll
  for (int t = 0; t < 4; t++) O[t] = (f32x4){0.f,0.f,0.f,0.f};
  #pragma unroll
  for (int r = 0; r < 4; r++) { rs[r] = 0.f; ts0[r] = 0.f; ts1[r] = 0.f; }

  for (int jt = 0; jt < 32; ++jt) {
    int cur = jt & 1;
    int k0 = jt << 5;
    __syncthreads();                    // stage(jt) complete; readers of buf cur^1 done
    if (jt < 31) STAGE(jt + 1, cur ^ 1);

    u32 pkc[8];
    #pragma unroll
    for (int e = 0; e < 8; e++) pkc[e] = pk[e];
    if (jt < 31) {
      int kn = (jt + 1) << 5;
      #pragma unroll
      for (int e = 0; e < 8; e++)
        pk[e] = pkb[((q0 + quad*4 + (e & 3)) << 10) + kn + (e >> 2)*16 + l15];
    }

    short8 kr00 = *(const short8*)&Kb[cur][kbo0];
    short8 kr01 = *(const short8*)&Kb[cur][kbo1];
    short8 kr10 = *(const short8*)&Kb[cur][1024 + kbo0];
    short8 kr11 = *(const short8*)&Kb[cur][1024 + kbo1];
    short8 vr[4];
    #pragma unroll
    for (int t = 0; t < 4; t++) vr[t] = *(const short8*)&Vb[cur][t*512 + vbo];

    f32x4 S0 = (f32x4){0.f,0.f,0.f,0.f}, S1 = (f32x4){0.f,0.f,0.f,0.f};
    __builtin_amdgcn_s_setprio(1);
    S0 = __builtin_amdgcn_mfma_f32_16x16x32_bf16(aQ[0], kr00, S0, 0, 0, 0);
    S0 = __builtin_amdgcn_mfma_f32_16x16x32_bf16(aQ[1], kr01, S0, 0, 0, 0);
    S1 = __builtin_amdgcn_mfma_f32_16x16x32_bf16(aQ[0], kr10, S1, 0, 0, 0);
    S1 = __builtin_amdgcn_mfma_f32_16x16x32_bf16(aQ[1], kr11, S1, 0, 0, 0);
    __builtin_amdgcn_s_setprio(0);
    f32x4 Scur[2] = { S0, S1 };

    if (jt < t_lo) {
      #pragma unroll
      for (int ct = 0; ct < 2; ct++) {
        float pv[4];
        #pragma unroll
        for (int r = 0; r < 4; r++) {
          u32 sg = pkc[ct*4 + r];
          float rw = __uint_as_float(sg & 0xffff0000u);
          float tb = __int_as_float(__builtin_amdgcn_ds_bpermute(
              (int)((sg & 63u) << 2), __float_as_int(treev)));
          float qm = (sg & 128u) ? -1e30f : qd0[r];
          float p = fexp2(__builtin_fmaf(tb, rw, Scur[ct][r] + qm));
          ts0[r] += p;
          pv[r] = p;
        }
        u32 c01 = cvtpk(pv[0], pv[1]), c23 = cvtpk(pv[2], pv[3]);
        u16* pl = &Pl[wv][(quad*4)*40 + ct*16 + l15];
        pl[0]   = (u16)c01; pl[40]  = (u16)(c01 >> 16);
        pl[80]  = (u16)c23; pl[120] = (u16)(c23 >> 16);
      }
    } else if (jt > t_hi) {
      #pragma unroll
      for (int ct = 0; ct < 2; ct++) {
        float pv[4];
        #pragma unroll
        for (int r = 0; r < 4; r++) {
          u32 sg = pkc[ct*4 + r];
          float rw = __uint_as_float(sg & 0xffff0000u);
          float tb = __int_as_float(__builtin_amdgcn_ds_bpermute(
              (int)((sg & 63u) << 2), __float_as_int(treev)));
          float qm = (sg & 128u) ? -1e30f : qd64[r];
          float p = fexp2(__builtin_fmaf(tb, rw, Scur[ct][r] + qm));
          ts1[r] += p;
          pv[r] = p;
        }
        u32 c01 = cvtpk(pv[0], pv[1]), c23 = cvtpk(pv[2], pv[3]);
        u16* pl = &Pl[wv][(quad*4)*40 + ct*16 + l15];
        pl[0]   = (u16)c01; pl[40]  = (u16)(c01 >> 16);
        pl[80]  = (u16)c23; pl[120] = (u16)(c23 >> 16);
      }
    } else {
      #pragma unroll
      for (int ct = 0; ct < 2; ct++) {
        float pv[4];
        #pragma unroll
        for (int r = 0; r < 4; r++) {
          int kloc = ct*16 + l15, qloc = quad*4 + r;
          int d = (k0 + kloc) - (q0 + qloc);
          int bucket = min(max(d + 32, 0), 64);
          u32 sg = pkc[ct*4 + r];
          float rw = __uint_as_float(sg & 0xffff0000u);
          float tb = __int_as_float(__builtin_amdgcn_ds_bpermute(
              (int)((sg & 63u) << 2), __float_as_int(treev)));
          float qd = bf2f(qdotL[(wv*16 + qloc)*68 + bucket]);
          float qm = (sg & 128u) ? -1e30f : qd;
          float p = fexp2(__builtin_fmaf(tb, rw, Scur[ct][r] + qm));
          if (d <= -32)      ts0[r] += p;
          else if (d >= 32)  ts1[r] += p;
          else             { rs[r] += p; PB[wv][qloc*96 + d + 32] = f2bf(p); }
          pv[r] = p;
        }
        u32 c01 = cvtpk(pv[0], pv[1]), c23 = cvtpk(pv[2], pv[3]);
        u16* pl = &Pl[wv][(quad*4)*40 + ct*16 + l15];
        pl[0]   = (u16)c01; pl[40]  = (u16)(c01 >> 16);
        pl[80]  = (u16)c23; pl[120] = (u16)(c23 >> 16);
      }
    }

    {
      short8 aP = *(const short8*)&Pl[wv][l15*40 + quad*8];
      __builtin_amdgcn_s_setprio(1);
      #pragma unroll
      for (int t = 0; t < 4; t++)
        O[t] = __builtin_amdgcn_mfma_f32_16x16x32_bf16(aP, vr[t], O[t], 0, 0, 0);
      __builtin_amdgcn_s_setprio(0);
    }
  }
#undef STAGE

  #pragma unroll
  for (int m = 1; m < 16; m <<= 1) {
    #pragma unroll
    for (int r = 0; r < 4; r++) {
      rs[r]  += __shfl_xor(rs[r],  m, 64);
      ts0[r] += __shfl_xor(ts0[r], m, 64);
      ts1[r] += __shfl_xor(ts1[r], m, 64);
    }
  }
  if (l15 == 0) {
    #pragma unroll
    for (int r = 0; r < 4; r++) {
      PB[wv][(quad*4 + r)*96 + 0]  = f2bf(ts0[r]);
      PB[wv][(quad*4 + r)*96 + 64] = f2bf(ts1[r]);
    }
  }
  // PB is per-wave: ds_write -> ds_read within the same wave, no barrier.

  {
    short8 aB[3];
    #pragma unroll
    for (int s = 0; s < 3; s++)
      aB[s] = *(const short8*)&PB[wv][l15*96 + s*32 + quad*8];
    #pragma unroll
    for (int t = 0; t < 4; t++)
      #pragma unroll
      for (int s = 0; s < 3; s++) {
        short8 bRV = *(const short8*)(relvT + (t*16 + l15)*96 + s*32 + quad*8);
        O[t] = __builtin_amdgcn_mfma_f32_16x16x32_bf16(aB[s], bRV, O[t], 0, 0, 0);
      }
  }

  {
    float inv[4];
    #pragma unroll
    for (int r = 0; r < 4; r++) inv[r] = 1.0f / (rs[r] + ts0[r] + ts1[r]);
    #pragma unroll
    for (int t = 0; t < 4; t++)
      #pragma unroll
      for (int r = 0; r < 4; r++) {
        int qg = q0 + quad*4 + r;
        ctx[(b*1024 + qg)*512 + h*64 + t*16 + l15] = f2bf(O[t][r] * inv[r]);
      }
  }
}

extern "C" void kernel_launch(void* const* d_in, const int* in_sizes, int n_in,
                              void* d_out, int out_size, void* d_ws, size_t ws_size,
                              hipStream_t stream) {
  const float* key   = (const float*)d_in[0];
  const float* value = (const float*)d_in[1];
  const float* query = (const float*)d_in[2];
  const unsigned char* maskp = (const unsigned char*)d_in[3];
  const int*   relm  = (const int*)d_in[4];
  const float* relw  = (const float*)d_in[5];
  const float* Wk = (const float*)d_in[6];
  const float* bk = (const float*)d_in[7];
  const float* Wq = (const float*)d_in[8];
  const float* bq = (const float*)d_in[9];
  const float* Wv = (const float*)d_in[10];
  const float* bv = (const float*)d_in[11];
  const float* Wo = (const float*)d_in[12];
  const float* bo = (const float*)d_in[13];
  const float* rek = (const float*)d_in[14];
  const float* rev = (const float*)d_in[15];
  const float* te  = (const float*)d_in[16];
  (void)in_sizes; (void)n_in; (void)out_size;

  char* w = (char*)d_ws;
  size_t off = 0;
  auto alloc = [&](size_t bytes) -> void* {
    void* p = w + off; off += (bytes + 255) & ~(size_t)255; return p;
  };
  u16* WkT = (u16*)alloc((size_t)512*512*2);
  u16* WqT = (u16*)alloc((size_t)512*512*2);
  u16* WvT = (u16*)alloc((size_t)512*512*2);
  u16* WoT = (u16*)alloc((size_t)512*512*2);
  u16* qws = (u16*)alloc((size_t)8*8*1024*64*2);   // [B,H,L,64], pre-scaled 0.125*log2e
  u16* kws = (u16*)alloc((size_t)8*8*1024*64*2);   // [B,H,L,64]
  u16* vt  = (u16*)alloc((size_t)8*8*1024*64*2);   // [B,H,64,L]
  u16* xq  = (u16*)alloc((size_t)8192*512*2);
  u16* xk  = (u16*)alloc((size_t)8192*512*2);
  u16* xv  = (u16*)alloc((size_t)8192*512*2);
  u32* packed = (u32*)alloc((size_t)8*1024*1024*4);
  u16* ctxb = (u16*)alloc((size_t)8192*512*2);     // [B,L,512] bf16
  u16* relk80 = (u16*)alloc((size_t)80*64*2);
  u16* relvT  = (u16*)alloc((size_t)64*96*2);
  if (off > ws_size) return;

  k_pre<<<21548, 256, 0, stream>>>(Wk, Wq, Wv, Wo, WkT, WqT, WvT, WoT,
                                   rek, rev, relk80, relvT,
                                   query, key, value, xq, xk, xv,
                                   relm, relw, maskp, packed);

  // Q pre-scaled by 0.125 * log2(e): softmax computed in exp2 domain.
  GArg aq { xq, WqT, bq, (void*)qws, 1, 0.18033688f };
  GArg ak { xk, WkT, bk, (void*)kws, 1, 1.0f };
  GArg av { xv, WvT, bv, (void*)vt,  2, 1.0f };
  k_gemm<<<dim3(4,64,3), 256, 0, stream>>>(aq, ak, av);

  k_attn<<<dim3(8,8,8), 512, 0, stream>>>(qws, kws, vt, relk80, relvT, te, packed, ctxb);

  GArg ao { ctxb, WoT, bo, d_out, 0, 1.0f };
  k_gemm<<<dim3(4,64,1), 256, 0, stream>>>(ao, ao, ao);
}

// Round 10
// 287.120 us; speedup vs baseline: 1.4186x; 1.0025x over previous
//
#include <hip/hip_runtime.h>
#include <stdint.h>

using f32x4  = __attribute__((ext_vector_type(4))) float;
using short8 = __attribute__((ext_vector_type(8))) short;
typedef unsigned short u16;
typedef unsigned int   u32;

// B=8, H=8, L=1024, DM=512, DK=DV=64.  M = B*L = 8192.

static __device__ __forceinline__ u16 f2bf(float f) {
  union { float f; u32 u; } v; v.f = f;
  u32 r = v.u + 0x7fffu + ((v.u >> 16) & 1u);   // RNE
  return (u16)(r >> 16);
}
static __device__ __forceinline__ float bf2f(u16 u) {
  union { u32 u; float f; } v; v.u = ((u32)u) << 16;
  return v.f;
}
static __device__ __forceinline__ float fexp2(float x) {
  float r;
  asm("v_exp_f32 %0, %1" : "=v"(r) : "v"(x));
  return r;
}
static __device__ __forceinline__ u32 cvtpk(float a, float b) {
  u32 r;
  asm("v_cvt_pk_bf16_f32 %0, %1, %2" : "=v"(r) : "v"(a), "v"(b));
  return r;
}

// async global->LDS, 16B per lane; LDS dest = wave-uniform base + lane*16
#define GLDS16(g, l) __builtin_amdgcn_global_load_lds( \
    (const __attribute__((address_space(1))) u32*)(g), \
    (__attribute__((address_space(3))) u32*)(l), 16, 0, 0)

// ---------------- fused preprocessing (R14: cvt section removed -> fused
// into k_gemmf A-staging; 21548 -> 9260 blocks) ----------------
// blocks [0,1024): weight transposes W[512k][512n] -> Wt[n][k] bf16 (4 mats)
// blocks [1024,1068): rel embeddings relk80/relvT
// blocks [1068,9260): pack rel_matrix|mask|bf16(rel_mask)
__global__ __launch_bounds__(256) void k_pre(
    const float* __restrict__ W0, const float* __restrict__ W1,
    const float* __restrict__ W2, const float* __restrict__ W3,
    u16* __restrict__ T0, u16* __restrict__ T1, u16* __restrict__ T2, u16* __restrict__ T3,
    const float* __restrict__ rk, const float* __restrict__ rv,
    u16* __restrict__ relk80, u16* __restrict__ relvT,
    const int* __restrict__ rm, const float* __restrict__ rw,
    const unsigned char* __restrict__ mk, u32* __restrict__ outp) {
  __shared__ float t[32][33];
  int bid = blockIdx.x, tid = threadIdx.x;
  if (bid < 1024) {
    int mat = bid >> 8, rem = bid & 255;
    const float* W = (mat == 0) ? W0 : (mat == 1) ? W1 : (mat == 2) ? W2 : W3;
    u16* T = (mat == 0) ? T0 : (mat == 1) ? T1 : (mat == 2) ? T2 : T3;
    int tx = tid & 31, ty = tid >> 5;
    int x0 = (rem & 15) * 32, y0 = (rem >> 4) * 32;
    #pragma unroll
    for (int i = 0; i < 4; i++)
      t[ty + i*8][tx] = W[(y0 + ty + i*8) * 512 + (x0 + tx)];
    __syncthreads();
    #pragma unroll
    for (int i = 0; i < 4; i++)
      T[(x0 + ty + i*8) * 512 + (y0 + tx)] = f2bf(t[tx][ty + i*8]);
  } else if (bid < 1068) {
    int i = (bid - 1024) * 256 + tid;
    if (i < 80*64) {
      int row = i >> 6;
      relk80[i] = (row < 65) ? f2bf(rk[i]) : (u16)0;
    }
    int j = i - 80*64;
    if (j >= 0 && j < 64*96) {
      int dv = j / 96, bk = j % 96;
      relvT[j] = (bk < 65) ? f2bf(rv[bk*64 + dv]) : (u16)0;
    }
  } else {
    int i = (bid - 1068) * 256 + tid;     // x4 elements
    int4   r4 = ((const int4*)rm)[i];
    float4 w4 = ((const float4*)rw)[i];
    uchar4 m4 = ((const uchar4*)mk)[i];
    uint4 o;
    o.x = (u32)(r4.x & 63) | (m4.x ? 128u : 0u) | ((u32)f2bf(w4.x) << 16);
    o.y = (u32)(r4.y & 63) | (m4.y ? 128u : 0u) | ((u32)f2bf(w4.y) << 16);
    o.z = (u32)(r4.z & 63) | (m4.z ? 128u : 0u) | ((u32)f2bf(w4.z) << 16);
    o.w = (u32)(r4.w & 63) | (m4.w ? 128u : 0u) | ((u32)f2bf(w4.w) << 16);
    ((uint4*)outp)[i] = o;
  }
}

// ---- R14: QKV GEMM reads fp32 A directly, cvt fused into reg-staged
// A-staging (kills the cvt3 pass: 72MB traffic + 12288 k_pre blocks).
// A-tile write layout = identical chunk layout GLDS16 produced: thread t
// covers chunks 2t,2t+1 (row=t>>1, k=(t&1)*16..+15), linear 32B/thread ->
// conflict-free ds_write_b128 x2. One barrier/step: loads for ks+1 issued
// BEFORE the barrier (reg dest, no LDS hazard); ds_write + B-GLDS16 after.
struct FArg { const float* A; const u16* Wt; const float* bias; void* out; int mode; float scale; };
struct GArg { const u16* A; const u16* Wt; const float* bias; void* out; int mode; float scale; };

__global__ __launch_bounds__(256, 3) void k_gemmf(FArg g0, FArg g1, FArg g2) {
  FArg ar = (blockIdx.z == 0) ? g0 : (blockIdx.z == 1) ? g1 : g2;
  __shared__ char smem_[34816];
  u16* As = (u16*)smem_;             // [2][4096] u16
  u16* Bs = (u16*)(smem_ + 16384);   // [2][4096] u16
  u16* Cs = (u16*)smem_;             // epilogue staging [128][136] (after barrier)
  int tid = threadIdx.x, lane = tid & 63, wv = tid >> 6;
  int quad = lane >> 4, l15 = lane & 15;
  int n0 = blockIdx.x * 128, m0 = blockIdx.y * 128;
  int wm = (wv >> 1) * 64, wn = (wv & 1) * 64;
  f32x4 acc[4][4];
  #pragma unroll
  for (int i = 0; i < 4; i++)
    #pragma unroll
    for (int j = 0; j < 4; j++)
      acc[i][j] = (f32x4){0.f, 0.f, 0.f, 0.f};

  const float* Asrc = ar.A + (size_t)(m0 + (tid >> 1)) * 512 + (tid & 1) * 16;
  const u16* Bbase = ar.Wt + (size_t)n0 * 512;
  int c0 = wv * 128;

  float4 fA[4];
#define LOADA(kt) do { _Pragma("unroll") \
    for (int i = 0; i < 4; i++) fA[i] = *(const float4*)(Asrc + (kt)*32 + i*4); } while (0)
#define WRITEA(nb) do { \
    u32 w0 = cvtpk(fA[0].x, fA[0].y), w1 = cvtpk(fA[0].z, fA[0].w); \
    u32 w2 = cvtpk(fA[1].x, fA[1].y), w3 = cvtpk(fA[1].z, fA[1].w); \
    u32 w4 = cvtpk(fA[2].x, fA[2].y), w5 = cvtpk(fA[2].z, fA[2].w); \
    u32 w6 = cvtpk(fA[3].x, fA[3].y), w7 = cvtpk(fA[3].z, fA[3].w); \
    ((uint4*)&As[(nb)*4096 + tid*16])[0] = make_uint4(w0, w1, w2, w3); \
    ((uint4*)&As[(nb)*4096 + tid*16])[1] = make_uint4(w4, w5, w6, w7); } while (0)
#define GLDSB(kt, nb) do { _Pragma("unroll") \
    for (int i = 0; i < 2; i++) { \
      int c = c0 + i*64 + lane; \
      GLDS16(Bbase + (c >> 2)*512 + (kt)*32 + (c & 3)*8, &Bs[(nb)*4096 + (c0 + i*64)*8]); \
    } } while (0)

  LOADA(0);
  WRITEA(0);
  GLDSB(0, 0);

  for (int ks = 0; ks < 16; ks++) {
    int cur = ks & 1;
    if (ks < 15) LOADA(ks + 1);        // global->reg, no LDS hazard, pre-barrier
    __syncthreads();                    // B(ks) landed; buf cur^1 readers done
    if (ks < 15) { WRITEA(cur ^ 1); GLDSB(ks + 1, cur ^ 1); }
    int bs = cur * 4096;
    short8 af[4], bf[4];
    #pragma unroll
    for (int i = 0; i < 4; i++) af[i] = *(const short8*)&As[bs + (wm + i*16 + l15)*32 + quad*8];
    #pragma unroll
    for (int j = 0; j < 4; j++) bf[j] = *(const short8*)&Bs[bs + (wn + j*16 + l15)*32 + quad*8];
    __builtin_amdgcn_s_setprio(1);
    #pragma unroll
    for (int i = 0; i < 4; i++)
      #pragma unroll
      for (int j = 0; j < 4; j++)
        acc[i][j] = __builtin_amdgcn_mfma_f32_16x16x32_bf16(af[i], bf[j], acc[i][j], 0, 0, 0);
    __builtin_amdgcn_s_setprio(0);
  }
#undef LOADA
#undef WRITEA
#undef GLDSB
  __syncthreads();                     // drain before Cs aliases As/Bs

  {
    #pragma unroll
    for (int i = 0; i < 4; i++)
      #pragma unroll
      for (int j = 0; j < 4; j++) {
        int nloc = wn + j*16 + l15;
        float bv = ar.bias[n0 + nloc];
        #pragma unroll
        for (int r = 0; r < 4; r++) {
          int mloc = wm + i*16 + quad*4 + r;
          float val = (acc[i][j][r] + bv) * ar.scale;
          if (ar.mode == 1) Cs[mloc*136 + nloc] = f2bf(val);
          else              Cs[nloc*136 + mloc] = f2bf(val);
        }
      }
    __syncthreads();
    int bb = m0 >> 10, hh0 = n0 >> 6, mbase = m0 & 1023;
    u16* outp = (u16*)ar.out;
    if (ar.mode == 1) {
      #pragma unroll
      for (int p = 0; p < 8; p++) {
        int mloc = (tid >> 4) + p*16, seg = tid & 15;
        int head = hh0 + (seg >> 3);
        size_t base = ((size_t)(bb*8 + head)*1024 + mbase)*64;
        *(short8*)(outp + base + (size_t)mloc*64 + (seg & 7)*8) =
            *(const short8*)&Cs[mloc*136 + seg*8];
      }
    } else {
      #pragma unroll
      for (int p = 0; p < 8; p++) {
        int nloc = (tid >> 4) + p*16, seg = tid & 15;
        int head = hh0 + (nloc >> 6), d = nloc & 63;
        size_t base = (size_t)(bb*8 + head)*64*1024 + mbase;
        *(short8*)(outp + base + (size_t)d*1024 + seg*8) =
            *(const short8*)&Cs[nloc*136 + seg*8];
      }
    }
  }
}

// ---------------- bf16-A GEMM (Wo): unchanged R13 structure ---------------
__global__ __launch_bounds__(256, 4) void k_gemm(GArg g0, GArg g1, GArg g2) {
  GArg ar = (blockIdx.z == 0) ? g0 : (blockIdx.z == 1) ? g1 : g2;
  __shared__ char smem_[34816];
  u16* As = (u16*)smem_;
  u16* Bs = (u16*)(smem_ + 16384);
  u16* Cs = (u16*)smem_;
  int tid = threadIdx.x, lane = tid & 63, wv = tid >> 6;
  int quad = lane >> 4, l15 = lane & 15;
  int n0 = blockIdx.x * 128, m0 = blockIdx.y * 128;
  int wm = (wv >> 1) * 64, wn = (wv & 1) * 64;
  f32x4 acc[4][4];
  #pragma unroll
  for (int i = 0; i < 4; i++)
    #pragma unroll
    for (int j = 0; j < 4; j++)
      acc[i][j] = (f32x4){0.f, 0.f, 0.f, 0.f};

  const u16* Abase = ar.A  + (size_t)m0 * 512;
  const u16* Bbase = ar.Wt + (size_t)n0 * 512;
  int c0 = wv * 128;

#define STAGEG(kt, nb) do { \
    _Pragma("unroll") \
    for (int i = 0; i < 2; i++) { \
      int c = c0 + i*64 + lane; \
      GLDS16(Abase + (c >> 2)*512 + (kt)*32 + (c & 3)*8, &As[(nb)*4096 + (c0 + i*64)*8]); \
      GLDS16(Bbase + (c >> 2)*512 + (kt)*32 + (c & 3)*8, &Bs[(nb)*4096 + (c0 + i*64)*8]); \
    } } while (0)

  STAGEG(0, 0);

  for (int ks = 0; ks < 16; ks++) {
    int cur = ks & 1;
    __syncthreads();
    if (ks < 15) STAGEG(ks + 1, cur ^ 1);
    int bs = cur * 4096;
    short8 af[4], bf[4];
    #pragma unroll
    for (int i = 0; i < 4; i++) af[i] = *(const short8*)&As[bs + (wm + i*16 + l15)*32 + quad*8];
    #pragma unroll
    for (int j = 0; j < 4; j++) bf[j] = *(const short8*)&Bs[bs + (wn + j*16 + l15)*32 + quad*8];
    __builtin_amdgcn_s_setprio(1);
    #pragma unroll
    for (int i = 0; i < 4; i++)
      #pragma unroll
      for (int j = 0; j < 4; j++)
        acc[i][j] = __builtin_amdgcn_mfma_f32_16x16x32_bf16(af[i], bf[j], acc[i][j], 0, 0, 0);
    __builtin_amdgcn_s_setprio(0);
  }
#undef STAGEG
  __syncthreads();

  if (ar.mode == 0) {
    #pragma unroll
    for (int i = 0; i < 4; i++)
      #pragma unroll
      for (int j = 0; j < 4; j++) {
        int ncol = n0 + wn + j*16 + l15;
        float bv = ar.bias[ncol];
        #pragma unroll
        for (int r = 0; r < 4; r++) {
          int m = m0 + wm + i*16 + quad*4 + r;
          ((float*)ar.out)[m*512 + ncol] = (acc[i][j][r] + bv) * ar.scale;
        }
      }
  } else {
    #pragma unroll
    for (int i = 0; i < 4; i++)
      #pragma unroll
      for (int j = 0; j < 4; j++) {
        int nloc = wn + j*16 + l15;
        float bv = ar.bias[n0 + nloc];
        #pragma unroll
        for (int r = 0; r < 4; r++) {
          int mloc = wm + i*16 + quad*4 + r;
          float val = (acc[i][j][r] + bv) * ar.scale;
          if (ar.mode == 1) Cs[mloc*136 + nloc] = f2bf(val);
          else              Cs[nloc*136 + mloc] = f2bf(val);
        }
      }
    __syncthreads();
    int bb = m0 >> 10, hh0 = n0 >> 6, mbase = m0 & 1023;
    u16* outp = (u16*)ar.out;
    if (ar.mode == 1) {
      #pragma unroll
      for (int p = 0; p < 8; p++) {
        int mloc = (tid >> 4) + p*16, seg = tid & 15;
        int head = hh0 + (seg >> 3);
        size_t base = ((size_t)(bb*8 + head)*1024 + mbase)*64;
        *(short8*)(outp + base + (size_t)mloc*64 + (seg & 7)*8) =
            *(const short8*)&Cs[mloc*136 + seg*8];
      }
    } else {
      #pragma unroll
      for (int p = 0; p < 8; p++) {
        int nloc = (tid >> 4) + p*16, seg = tid & 15;
        int head = hh0 + (nloc >> 6), d = nloc & 63;
        size_t base = (size_t)(bb*8 + head)*64*1024 + mbase;
        *(short8*)(outp + base + (size_t)d*1024 + seg*8) =
            *(const short8*)&Cs[nloc*136 + seg*8];
      }
    }
  }
}

// ---------------- fused attention ----------------
// R14: grid order reverted to R12 (id%8 = qb): the 8 h-siblings sharing
// packed[b] rows co-locate on one XCD. R13's h-major order re-fetched
// packed ~5x (FETCH 86->146MB) for zero dur gain -- falsified; reverted.
__global__ __launch_bounds__(512, 4) void k_attn(
    const u16* __restrict__ qws, const u16* __restrict__ kws, const u16* __restrict__ vtws,
    const u16* __restrict__ relk80, const u16* __restrict__ relvT,
    const float* __restrict__ tree_emb, const u32* __restrict__ packed,
    u16* __restrict__ ctx) {
  __shared__ u16 Kb[2][2048];       // [buf][32 k-rows][64 d] swizzled
  __shared__ u16 Vb[2][2048];       // [buf][64 d-rows][32 k] swizzled
  __shared__ u16 qdotL[8*16*68];    // [w][q][bucket]  (band tiles)
  __shared__ u16 PB[8][16*96];      // per-wave banded P
  __shared__ u16 Pl[8][16*40];      // per-wave C->A bridge, stride 40

  int tid = threadIdx.x, lane = tid & 63, wv = tid >> 6;
  int quad = lane >> 4, l15 = lane & 15;
  int qb = blockIdx.x, h = blockIdx.y, b = blockIdx.z;
  int q0 = qb * 128 + wv * 16;

  // register tree table: lane v (0..63) holds tree_emb[v][h] * log2e
  float treev = tree_emb[lane * 8 + h] * 1.44269504f;

  #pragma unroll
  for (int i = 0; i < 12; i++) ((u32*)&PB[wv][0])[lane + i*64] = 0u;

  const u16* qp = qws  + (size_t)(b*8 + h)*(1024*64);
  const u16* kp = kws  + (size_t)(b*8 + h)*(1024*64);
  const u16* vp = vtws + (size_t)(b*8 + h)*(64*1024);
  const u32* pkb = packed + ((size_t)b << 20);

  // staging roles: waves 0-3 carry K rows; waves 4-7 carry V rows.
  int rk = (wv & 3)*8 + (lane >> 3);
  int swk = (((lane & 7)*8) ^ ((rk & 7) << 3));
  int rv = (wv & 3)*16 + (lane >> 2);
  const u16* vsrc = vp + (size_t)rv*1024 + (((lane & 3)*8) ^ ((rv & 3) << 3));

#define STAGE(kt, nb) do { \
    if (wv < 4) GLDS16(kp + (size_t)((kt)*32 + rk)*64 + swk, &Kb[nb][wv*512]); \
    else        GLDS16(vsrc + (kt)*32, &Vb[nb][(wv & 3)*512]); \
  } while (0)

  STAGE(0, 0);

  short8 aQ[2];
  #pragma unroll
  for (int kf = 0; kf < 2; kf++)
    aQ[kf] = *(const short8*)(qp + (q0 + l15)*64 + kf*32 + quad*8);

  float qd0[4], qd64[4];
  #pragma unroll
  for (int t = 0; t < 5; t++) {
    f32x4 C = (f32x4){0.f,0.f,0.f,0.f};
    #pragma unroll
    for (int kf = 0; kf < 2; kf++) {
      short8 bR = *(const short8*)(relk80 + (t*16 + l15)*64 + kf*32 + quad*8);
      C = __builtin_amdgcn_mfma_f32_16x16x32_bf16(aQ[kf], bR, C, 0, 0, 0);
    }
    if (t == 0) {
      #pragma unroll
      for (int r = 0; r < 4; r++) qd0[r] = __shfl(C[r], lane & 48, 64);
    }
    if (t == 4) {
      #pragma unroll
      for (int r = 0; r < 4; r++) qd64[r] = __shfl(C[r], lane & 48, 64);
    }
    int col = t*16 + l15;
    if (col < 65) {
      #pragma unroll
      for (int r = 0; r < 4; r++)
        qdotL[(wv*16 + quad*4 + r)*68 + col] = f2bf(C[r]);
    }
  }

  int t_lo = max(0, (q0 - 31) >> 5);
  int t_hi = min(31, (q0 + 46) >> 5);

  // precomputed LDS read offsets (u16 units); ct adds 1024, t adds 512
  int sK = (l15 & 7) << 3;
  int kbo0 = l15*64 + ((quad*8) ^ sK);          // kf=0
  int kbo1 = l15*64 + (((4 + quad)*8) ^ sK);    // kf=1
  int vbo  = l15*32 + ((quad*8) ^ ((l15 & 3) << 3));

  u32 pk[8];
  #pragma unroll
  for (int e = 0; e < 8; e++)
    pk[e] = pkb[((q0 + quad*4 + (e & 3)) << 10) + (e >> 2)*16 + l15];

  f32x4 O[4];
  float rs[4], ts0[4], ts1[4];
  #pragma unroll
  for (int t = 0; t < 4; t++) O[t] = (f32x4){0.f,0.f,0.f,0.f};
  #pragma unroll
  for (int r = 0; r < 4; r++) { rs[r] = 0.f; ts0[r] = 0.f; ts1[r] = 0.f; }

  for (int jt = 0; jt < 32; ++jt) {
    int cur = jt & 1;
    int k0 = jt << 5;
    __syncthreads();                    // stage(jt) complete; readers of buf cur^1 done
    if (jt < 31) STAGE(jt + 1, cur ^ 1);

    u32 pkc[8];
    #pragma unroll
    for (int e = 0; e < 8; e++) pkc[e] = pk[e];
    if (jt < 31) {
      int kn = (jt + 1) << 5;
      #pragma unroll
      for (int e = 0; e < 8; e++)
        pk[e] = pkb[((q0 + quad*4 + (e & 3)) << 10) + kn + (e >> 2)*16 + l15];
    }

    short8 kr00 = *(const short8*)&Kb[cur][kbo0];
    short8 kr01 = *(const short8*)&Kb[cur][kbo1];
    short8 kr10 = *(const short8*)&Kb[cur][1024 + kbo0];
    short8 kr11 = *(const short8*)&Kb[cur][1024 + kbo1];
    short8 vr[4];
    #pragma unroll
    for (int t = 0; t < 4; t++) vr[t] = *(const short8*)&Vb[cur][t*512 + vbo];

    f32x4 S0 = (f32x4){0.f,0.f,0.f,0.f}, S1 = (f32x4){0.f,0.f,0.f,0.f};
    __builtin_amdgcn_s_setprio(1);
    S0 = __builtin_amdgcn_mfma_f32_16x16x32_bf16(aQ[0], kr00, S0, 0, 0, 0);
    S0 = __builtin_amdgcn_mfma_f32_16x16x32_bf16(aQ[1], kr01, S0, 0, 0, 0);
    S1 = __builtin_amdgcn_mfma_f32_16x16x32_bf16(aQ[0], kr10, S1, 0, 0, 0);
    S1 = __builtin_amdgcn_mfma_f32_16x16x32_bf16(aQ[1], kr11, S1, 0, 0, 0);
    __builtin_amdgcn_s_setprio(0);
    f32x4 Scur[2] = { S0, S1 };

    if (jt < t_lo) {
      #pragma unroll
      for (int ct = 0; ct < 2; ct++) {
        float pv[4];
        #pragma unroll
        for (int r = 0; r < 4; r++) {
          u32 sg = pkc[ct*4 + r];
          float rw = __uint_as_float(sg & 0xffff0000u);
          float tb = __int_as_float(__builtin_amdgcn_ds_bpermute(
              (int)((sg & 63u) << 2), __float_as_int(treev)));
          float qm = (sg & 128u) ? -1e30f : qd0[r];
          float p = fexp2(__builtin_fmaf(tb, rw, Scur[ct][r] + qm));
          ts0[r] += p;
          pv[r] = p;
        }
        u32 c01 = cvtpk(pv[0], pv[1]), c23 = cvtpk(pv[2], pv[3]);
        u16* pl = &Pl[wv][(quad*4)*40 + ct*16 + l15];
        pl[0]   = (u16)c01; pl[40]  = (u16)(c01 >> 16);
        pl[80]  = (u16)c23; pl[120] = (u16)(c23 >> 16);
      }
    } else if (jt > t_hi) {
      #pragma unroll
      for (int ct = 0; ct < 2; ct++) {
        float pv[4];
        #pragma unroll
        for (int r = 0; r < 4; r++) {
          u32 sg = pkc[ct*4 + r];
          float rw = __uint_as_float(sg & 0xffff0000u);
          float tb = __int_as_float(__builtin_amdgcn_ds_bpermute(
              (int)((sg & 63u) << 2), __float_as_int(treev)));
          float qm = (sg & 128u) ? -1e30f : qd64[r];
          float p = fexp2(__builtin_fmaf(tb, rw, Scur[ct][r] + qm));
          ts1[r] += p;
          pv[r] = p;
        }
        u32 c01 = cvtpk(pv[0], pv[1]), c23 = cvtpk(pv[2], pv[3]);
        u16* pl = &Pl[wv][(quad*4)*40 + ct*16 + l15];
        pl[0]   = (u16)c01; pl[40]  = (u16)(c01 >> 16);
        pl[80]  = (u16)c23; pl[120] = (u16)(c23 >> 16);
      }
    } else {
      #pragma unroll
      for (int ct = 0; ct < 2; ct++) {
        float pv[4];
        #pragma unroll
        for (int r = 0; r < 4; r++) {
          int kloc = ct*16 + l15, qloc = quad*4 + r;
          int d = (k0 + kloc) - (q0 + qloc);
          int bucket = min(max(d + 32, 0), 64);
          u32 sg = pkc[ct*4 + r];
          float rw = __uint_as_float(sg & 0xffff0000u);
          float tb = __int_as_float(__builtin_amdgcn_ds_bpermute(
              (int)((sg & 63u) << 2), __float_as_int(treev)));
          float qd = bf2f(qdotL[(wv*16 + qloc)*68 + bucket]);
          float qm = (sg & 128u) ? -1e30f : qd;
          float p = fexp2(__builtin_fmaf(tb, rw, Scur[ct][r] + qm));
          if (d <= -32)      ts0[r] += p;
          else if (d >= 32)  ts1[r] += p;
          else             { rs[r] += p; PB[wv][qloc*96 + d + 32] = f2bf(p); }
          pv[r] = p;
        }
        u32 c01 = cvtpk(pv[0], pv[1]), c23 = cvtpk(pv[2], pv[3]);
        u16* pl = &Pl[wv][(quad*4)*40 + ct*16 + l15];
        pl[0]   = (u16)c01; pl[40]  = (u16)(c01 >> 16);
        pl[80]  = (u16)c23; pl[120] = (u16)(c23 >> 16);
      }
    }

    {
      short8 aP = *(const short8*)&Pl[wv][l15*40 + quad*8];
      __builtin_amdgcn_s_setprio(1);
      #pragma unroll
      for (int t = 0; t < 4; t++)
        O[t] = __builtin_amdgcn_mfma_f32_16x16x32_bf16(aP, vr[t], O[t], 0, 0, 0);
      __builtin_amdgcn_s_setprio(0);
    }
  }
#undef STAGE

  #pragma unroll
  for (int m = 1; m < 16; m <<= 1) {
    #pragma unroll
    for (int r = 0; r < 4; r++) {
      rs[r]  += __shfl_xor(rs[r],  m, 64);
      ts0[r] += __shfl_xor(ts0[r], m, 64);
      ts1[r] += __shfl_xor(ts1[r], m, 64);
    }
  }
  if (l15 == 0) {
    #pragma unroll
    for (int r = 0; r < 4; r++) {
      PB[wv][(quad*4 + r)*96 + 0]  = f2bf(ts0[r]);
      PB[wv][(quad*4 + r)*96 + 64] = f2bf(ts1[r]);
    }
  }
  // PB is per-wave: ds_write -> ds_read within the same wave, no barrier.

  {
    short8 aB[3];
    #pragma unroll
    for (int s = 0; s < 3; s++)
      aB[s] = *(const short8*)&PB[wv][l15*96 + s*32 + quad*8];
    #pragma unroll
    for (int t = 0; t < 4; t++)
      #pragma unroll
      for (int s = 0; s < 3; s++) {
        short8 bRV = *(const short8*)(relvT + (t*16 + l15)*96 + s*32 + quad*8);
        O[t] = __builtin_amdgcn_mfma_f32_16x16x32_bf16(aB[s], bRV, O[t], 0, 0, 0);
      }
  }

  {
    float inv[4];
    #pragma unroll
    for (int r = 0; r < 4; r++) inv[r] = 1.0f / (rs[r] + ts0[r] + ts1[r]);
    #pragma unroll
    for (int t = 0; t < 4; t++)
      #pragma unroll
      for (int r = 0; r < 4; r++) {
        int qg = q0 + quad*4 + r;
        ctx[(b*1024 + qg)*512 + h*64 + t*16 + l15] = f2bf(O[t][r] * inv[r]);
      }
  }
}

extern "C" void kernel_launch(void* const* d_in, const int* in_sizes, int n_in,
                              void* d_out, int out_size, void* d_ws, size_t ws_size,
                              hipStream_t stream) {
  const float* key   = (const float*)d_in[0];
  const float* value = (const float*)d_in[1];
  const float* query = (const float*)d_in[2];
  const unsigned char* maskp = (const unsigned char*)d_in[3];
  const int*   relm  = (const int*)d_in[4];
  const float* relw  = (const float*)d_in[5];
  const float* Wk = (const float*)d_in[6];
  const float* bk = (const float*)d_in[7];
  const float* Wq = (const float*)d_in[8];
  const float* bq = (const float*)d_in[9];
  const float* Wv = (const float*)d_in[10];
  const float* bv = (const float*)d_in[11];
  const float* Wo = (const float*)d_in[12];
  const float* bo = (const float*)d_in[13];
  const float* rek = (const float*)d_in[14];
  const float* rev = (const float*)d_in[15];
  const float* te  = (const float*)d_in[16];
  (void)in_sizes; (void)n_in; (void)out_size;

  char* w = (char*)d_ws;
  size_t off = 0;
  auto alloc = [&](size_t bytes) -> void* {
    void* p = w + off; off += (bytes + 255) & ~(size_t)255; return p;
  };
  u16* WkT = (u16*)alloc((size_t)512*512*2);
  u16* WqT = (u16*)alloc((size_t)512*512*2);
  u16* WvT = (u16*)alloc((size_t)512*512*2);
  u16* WoT = (u16*)alloc((size_t)512*512*2);
  u16* qws = (u16*)alloc((size_t)8*8*1024*64*2);   // [B,H,L,64], pre-scaled 0.125*log2e
  u16* kws = (u16*)alloc((size_t)8*8*1024*64*2);   // [B,H,L,64]
  u16* vt  = (u16*)alloc((size_t)8*8*1024*64*2);   // [B,H,64,L]
  u32* packed = (u32*)alloc((size_t)8*1024*1024*4);
  u16* ctxb = (u16*)alloc((size_t)8192*512*2);     // [B,L,512] bf16
  u16* relk80 = (u16*)alloc((size_t)80*64*2);
  u16* relvT  = (u16*)alloc((size_t)64*96*2);
  if (off > ws_size) return;

  k_pre<<<9260, 256, 0, stream>>>(Wk, Wq, Wv, Wo, WkT, WqT, WvT, WoT,
                                  rek, rev, relk80, relvT,
                                  relm, relw, maskp, packed);

  // Q pre-scaled by 0.125 * log2(e): softmax computed in exp2 domain.
  FArg aq { query, WqT, bq, (void*)qws, 1, 0.18033688f };
  FArg ak { key,   WkT, bk, (void*)kws, 1, 1.0f };
  FArg av { value, WvT, bv, (void*)vt,  2, 1.0f };
  k_gemmf<<<dim3(4,64,3), 256, 0, stream>>>(aq, ak, av);

  k_attn<<<dim3(8,8,8), 512, 0, stream>>>(qws, kws, vt, relk80, relvT, te, packed, ctxb);

  GArg ao { ctxb, WoT, bo, d_out, 0, 1.0f };
  k_gemm<<<dim3(4,64,1), 256, 0, stream>>>(ao, ao, ao);
}

// Round 11
// 284.547 us; speedup vs baseline: 1.4314x; 1.0090x over previous
//
#include <hip/hip_runtime.h>
#include <stdint.h>

using f32x4  = __attribute__((ext_vector_type(4))) float;
using short8 = __attribute__((ext_vector_type(8))) short;
typedef unsigned short u16;
typedef unsigned int   u32;

// B=8, H=8, L=1024, DM=512, DK=DV=64.  M = B*L = 8192.

static __device__ __forceinline__ u16 f2bf(float f) {
  union { float f; u32 u; } v; v.f = f;
  u32 r = v.u + 0x7fffu + ((v.u >> 16) & 1u);   // RNE
  return (u16)(r >> 16);
}
static __device__ __forceinline__ float bf2f(u16 u) {
  union { u32 u; float f; } v; v.u = ((u32)u) << 16;
  return v.f;
}
static __device__ __forceinline__ float fexp2(float x) {
  float r;
  asm("v_exp_f32 %0, %1" : "=v"(r) : "v"(x));
  return r;
}
static __device__ __forceinline__ u32 cvtpk(float a, float b) {
  u32 r;
  asm("v_cvt_pk_bf16_f32 %0, %1, %2" : "=v"(r) : "v"(a), "v"(b));
  return r;
}

// async global->LDS, 16B per lane; LDS dest = wave-uniform base + lane*16
#define GLDS16(g, l) __builtin_amdgcn_global_load_lds( \
    (const __attribute__((address_space(1))) u32*)(g), \
    (__attribute__((address_space(3))) u32*)(l), 16, 0, 0)

// ---------------- preprocessing (R15: pack moved into k_gemmf launch) -----
// blocks [0,1024): weight transposes W[512k][512n] -> Wt[n][k] bf16 (4 mats)
// blocks [1024,1068): rel embeddings relk80/relvT
__global__ __launch_bounds__(256) void k_pre(
    const float* __restrict__ W0, const float* __restrict__ W1,
    const float* __restrict__ W2, const float* __restrict__ W3,
    u16* __restrict__ T0, u16* __restrict__ T1, u16* __restrict__ T2, u16* __restrict__ T3,
    const float* __restrict__ rk, const float* __restrict__ rv,
    u16* __restrict__ relk80, u16* __restrict__ relvT) {
  __shared__ float t[32][33];
  int bid = blockIdx.x, tid = threadIdx.x;
  if (bid < 1024) {
    int mat = bid >> 8, rem = bid & 255;
    const float* W = (mat == 0) ? W0 : (mat == 1) ? W1 : (mat == 2) ? W2 : W3;
    u16* T = (mat == 0) ? T0 : (mat == 1) ? T1 : (mat == 2) ? T2 : T3;
    int tx = tid & 31, ty = tid >> 5;
    int x0 = (rem & 15) * 32, y0 = (rem >> 4) * 32;
    #pragma unroll
    for (int i = 0; i < 4; i++)
      t[ty + i*8][tx] = W[(y0 + ty + i*8) * 512 + (x0 + tx)];
    __syncthreads();
    #pragma unroll
    for (int i = 0; i < 4; i++)
      T[(x0 + ty + i*8) * 512 + (y0 + tx)] = f2bf(t[tx][ty + i*8]);
  } else {
    int i = (bid - 1024) * 256 + tid;
    if (i < 80*64) {
      int row = i >> 6;
      relk80[i] = (row < 65) ? f2bf(rk[i]) : (u16)0;
    }
    int j = i - 80*64;
    if (j >= 0 && j < 64*96) {
      int dv = j / 96, bk = j % 96;
      relvT[j] = (bk < 65) ? f2bf(rv[bk*64 + dv]) : (u16)0;
    }
  }
}

// ---- R15: QKV GEMM (fp32 A, cvt fused) + pack section in ONE launch.
// Blocks [0,768): GEMM tiles (z = bid>>8, x = bid&3, y = (bid>>2)&63).
// Blocks [768,8960): pack rel_matrix|mask|bf16(rel_mask) -> packed. Pack is
// independent of the GEMM (packed consumed only by the NEXT launch k_attn),
// so the trailing BW-bound blocks backfill GEMM latency bubbles; one launch
// boundary removed.
// Pipeline fix vs R14: LOADA was issued immediately pre-barrier -> the
// barrier's vmcnt(0) drain exposed full A-load latency every step. Now two
// fA register sets rotate; LOADA(ks+2) issues AFTER the barrier (post
// WRITEA+GLDSB), hidden under MFMA(ks).
struct FArg { const float* A; const u16* Wt; const float* bias; void* out; int mode; float scale; };
struct GArg { const u16* A; const u16* Wt; const float* bias; void* out; int mode; float scale; };

__global__ __launch_bounds__(256, 3) void k_gemmf(FArg g0, FArg g1, FArg g2,
    const int* __restrict__ rm, const float* __restrict__ rw,
    const unsigned char* __restrict__ mk, u32* __restrict__ outp) {
  int bid = blockIdx.x, tid = threadIdx.x;
  if (bid >= 768) {
    int i = (bid - 768) * 256 + tid;     // x4 elements
    int4   r4 = ((const int4*)rm)[i];
    float4 w4 = ((const float4*)rw)[i];
    uchar4 m4 = ((const uchar4*)mk)[i];
    uint4 o;
    o.x = (u32)(r4.x & 63) | (m4.x ? 128u : 0u) | ((u32)f2bf(w4.x) << 16);
    o.y = (u32)(r4.y & 63) | (m4.y ? 128u : 0u) | ((u32)f2bf(w4.y) << 16);
    o.z = (u32)(r4.z & 63) | (m4.z ? 128u : 0u) | ((u32)f2bf(w4.z) << 16);
    o.w = (u32)(r4.w & 63) | (m4.w ? 128u : 0u) | ((u32)f2bf(w4.w) << 16);
    ((uint4*)outp)[i] = o;
    return;
  }
  FArg ar = (bid < 256) ? g0 : (bid < 512) ? g1 : g2;
  __shared__ char smem_[34816];
  u16* As = (u16*)smem_;             // [2][4096] u16
  u16* Bs = (u16*)(smem_ + 16384);   // [2][4096] u16
  u16* Cs = (u16*)smem_;             // epilogue staging [128][136] (after barrier)
  int lane = tid & 63, wv = tid >> 6;
  int quad = lane >> 4, l15 = lane & 15;
  int n0 = (bid & 3) * 128, m0 = ((bid >> 2) & 63) * 128;
  int wm = (wv >> 1) * 64, wn = (wv & 1) * 64;
  f32x4 acc[4][4];
  #pragma unroll
  for (int i = 0; i < 4; i++)
    #pragma unroll
    for (int j = 0; j < 4; j++)
      acc[i][j] = (f32x4){0.f, 0.f, 0.f, 0.f};

  const float* Asrc = ar.A + (size_t)(m0 + (tid >> 1)) * 512 + (tid & 1) * 16;
  const u16* Bbase = ar.Wt + (size_t)n0 * 512;
  int c0 = wv * 128;

  float4 fA0[4], fA1[4];
#define LOADA(fa, kt) do { _Pragma("unroll") \
    for (int i = 0; i < 4; i++) fa[i] = *(const float4*)(Asrc + (kt)*32 + i*4); } while (0)
#define WRITEA(fa, nb) do { \
    u32 w0 = cvtpk(fa[0].x, fa[0].y), w1 = cvtpk(fa[0].z, fa[0].w); \
    u32 w2 = cvtpk(fa[1].x, fa[1].y), w3 = cvtpk(fa[1].z, fa[1].w); \
    u32 w4 = cvtpk(fa[2].x, fa[2].y), w5 = cvtpk(fa[2].z, fa[2].w); \
    u32 w6 = cvtpk(fa[3].x, fa[3].y), w7 = cvtpk(fa[3].z, fa[3].w); \
    ((uint4*)&As[(nb)*4096 + tid*16])[0] = make_uint4(w0, w1, w2, w3); \
    ((uint4*)&As[(nb)*4096 + tid*16])[1] = make_uint4(w4, w5, w6, w7); } while (0)
#define GLDSB(kt, nb) do { _Pragma("unroll") \
    for (int i = 0; i < 2; i++) { \
      int c = c0 + i*64 + lane; \
      GLDS16(Bbase + (c >> 2)*512 + (kt)*32 + (c & 3)*8, &Bs[(nb)*4096 + (c0 + i*64)*8]); \
    } } while (0)
#define MFMAS(nb) do { \
    int bs = (nb) * 4096; \
    short8 af[4], bf[4]; \
    _Pragma("unroll") \
    for (int i = 0; i < 4; i++) af[i] = *(const short8*)&As[bs + (wm + i*16 + l15)*32 + quad*8]; \
    _Pragma("unroll") \
    for (int j = 0; j < 4; j++) bf[j] = *(const short8*)&Bs[bs + (wn + j*16 + l15)*32 + quad*8]; \
    __builtin_amdgcn_s_setprio(1); \
    _Pragma("unroll") \
    for (int i = 0; i < 4; i++) \
      _Pragma("unroll") \
      for (int j = 0; j < 4; j++) \
        acc[i][j] = __builtin_amdgcn_mfma_f32_16x16x32_bf16(af[i], bf[j], acc[i][j], 0, 0, 0); \
    __builtin_amdgcn_s_setprio(0); } while (0)

  // prologue: tile0 staged; tile1 A-data in flight
  LOADA(fA0, 0);
  WRITEA(fA0, 0);
  GLDSB(0, 0);
  LOADA(fA1, 1);

  #pragma unroll 2
  for (int ks = 0; ks < 16; ks++) {
    __syncthreads();                   // buf(ks) ready (glds + ds_writes drained)
    if (ks & 1) {
      if (ks < 15) { WRITEA(fA0, (ks + 1) & 1); GLDSB(ks + 1, (ks + 1) & 1); }
      if (ks < 14) LOADA(fA1, ks + 2);
    } else {
      if (ks < 15) { WRITEA(fA1, (ks + 1) & 1); GLDSB(ks + 1, (ks + 1) & 1); }
      if (ks < 14) LOADA(fA0, ks + 2);
    }
    MFMAS(ks & 1);
  }
#undef LOADA
#undef WRITEA
#undef GLDSB
#undef MFMAS
  __syncthreads();                     // drain before Cs aliases As/Bs

  {
    #pragma unroll
    for (int i = 0; i < 4; i++)
      #pragma unroll
      for (int j = 0; j < 4; j++) {
        int nloc = wn + j*16 + l15;
        float bv = ar.bias[n0 + nloc];
        #pragma unroll
        for (int r = 0; r < 4; r++) {
          int mloc = wm + i*16 + quad*4 + r;
          float val = (acc[i][j][r] + bv) * ar.scale;
          if (ar.mode == 1) Cs[mloc*136 + nloc] = f2bf(val);
          else              Cs[nloc*136 + mloc] = f2bf(val);
        }
      }
    __syncthreads();
    int bb = m0 >> 10, hh0 = n0 >> 6, mbase = m0 & 1023;
    u16* outp2 = (u16*)ar.out;
    if (ar.mode == 1) {
      #pragma unroll
      for (int p = 0; p < 8; p++) {
        int mloc = (tid >> 4) + p*16, seg = tid & 15;
        int head = hh0 + (seg >> 3);
        size_t base = ((size_t)(bb*8 + head)*1024 + mbase)*64;
        *(short8*)(outp2 + base + (size_t)mloc*64 + (seg & 7)*8) =
            *(const short8*)&Cs[mloc*136 + seg*8];
      }
    } else {
      #pragma unroll
      for (int p = 0; p < 8; p++) {
        int nloc = (tid >> 4) + p*16, seg = tid & 15;
        int head = hh0 + (nloc >> 6), d = nloc & 63;
        size_t base = (size_t)(bb*8 + head)*64*1024 + mbase;
        *(short8*)(outp2 + base + (size_t)d*1024 + seg*8) =
            *(const short8*)&Cs[nloc*136 + seg*8];
      }
    }
  }
}

// ---------------- bf16-A GEMM (Wo): unchanged R13 structure ---------------
__global__ __launch_bounds__(256, 4) void k_gemm(GArg g0, GArg g1, GArg g2) {
  GArg ar = (blockIdx.z == 0) ? g0 : (blockIdx.z == 1) ? g1 : g2;
  __shared__ char smem_[34816];
  u16* As = (u16*)smem_;
  u16* Bs = (u16*)(smem_ + 16384);
  u16* Cs = (u16*)smem_;
  int tid = threadIdx.x, lane = tid & 63, wv = tid >> 6;
  int quad = lane >> 4, l15 = lane & 15;
  int n0 = blockIdx.x * 128, m0 = blockIdx.y * 128;
  int wm = (wv >> 1) * 64, wn = (wv & 1) * 64;
  f32x4 acc[4][4];
  #pragma unroll
  for (int i = 0; i < 4; i++)
    #pragma unroll
    for (int j = 0; j < 4; j++)
      acc[i][j] = (f32x4){0.f, 0.f, 0.f, 0.f};

  const u16* Abase = ar.A  + (size_t)m0 * 512;
  const u16* Bbase = ar.Wt + (size_t)n0 * 512;
  int c0 = wv * 128;

#define STAGEG(kt, nb) do { \
    _Pragma("unroll") \
    for (int i = 0; i < 2; i++) { \
      int c = c0 + i*64 + lane; \
      GLDS16(Abase + (c >> 2)*512 + (kt)*32 + (c & 3)*8, &As[(nb)*4096 + (c0 + i*64)*8]); \
      GLDS16(Bbase + (c >> 2)*512 + (kt)*32 + (c & 3)*8, &Bs[(nb)*4096 + (c0 + i*64)*8]); \
    } } while (0)

  STAGEG(0, 0);

  for (int ks = 0; ks < 16; ks++) {
    int cur = ks & 1;
    __syncthreads();
    if (ks < 15) STAGEG(ks + 1, cur ^ 1);
    int bs = cur * 4096;
    short8 af[4], bf[4];
    #pragma unroll
    for (int i = 0; i < 4; i++) af[i] = *(const short8*)&As[bs + (wm + i*16 + l15)*32 + quad*8];
    #pragma unroll
    for (int j = 0; j < 4; j++) bf[j] = *(const short8*)&Bs[bs + (wn + j*16 + l15)*32 + quad*8];
    __builtin_amdgcn_s_setprio(1);
    #pragma unroll
    for (int i = 0; i < 4; i++)
      #pragma unroll
      for (int j = 0; j < 4; j++)
        acc[i][j] = __builtin_amdgcn_mfma_f32_16x16x32_bf16(af[i], bf[j], acc[i][j], 0, 0, 0);
    __builtin_amdgcn_s_setprio(0);
  }
#undef STAGEG
  __syncthreads();

  if (ar.mode == 0) {
    #pragma unroll
    for (int i = 0; i < 4; i++)
      #pragma unroll
      for (int j = 0; j < 4; j++) {
        int ncol = n0 + wn + j*16 + l15;
        float bv = ar.bias[ncol];
        #pragma unroll
        for (int r = 0; r < 4; r++) {
          int m = m0 + wm + i*16 + quad*4 + r;
          ((float*)ar.out)[m*512 + ncol] = (acc[i][j][r] + bv) * ar.scale;
        }
      }
  } else {
    #pragma unroll
    for (int i = 0; i < 4; i++)
      #pragma unroll
      for (int j = 0; j < 4; j++) {
        int nloc = wn + j*16 + l15;
        float bv = ar.bias[n0 + nloc];
        #pragma unroll
        for (int r = 0; r < 4; r++) {
          int mloc = wm + i*16 + quad*4 + r;
          float val = (acc[i][j][r] + bv) * ar.scale;
          if (ar.mode == 1) Cs[mloc*136 + nloc] = f2bf(val);
          else              Cs[nloc*136 + mloc] = f2bf(val);
        }
      }
    __syncthreads();
    int bb = m0 >> 10, hh0 = n0 >> 6, mbase = m0 & 1023;
    u16* outp = (u16*)ar.out;
    if (ar.mode == 1) {
      #pragma unroll
      for (int p = 0; p < 8; p++) {
        int mloc = (tid >> 4) + p*16, seg = tid & 15;
        int head = hh0 + (seg >> 3);
        size_t base = ((size_t)(bb*8 + head)*1024 + mbase)*64;
        *(short8*)(outp + base + (size_t)mloc*64 + (seg & 7)*8) =
            *(const short8*)&Cs[mloc*136 + seg*8];
      }
    } else {
      #pragma unroll
      for (int p = 0; p < 8; p++) {
        int nloc = (tid >> 4) + p*16, seg = tid & 15;
        int head = hh0 + (nloc >> 6), d = nloc & 63;
        size_t base = (size_t)(bb*8 + head)*64*1024 + mbase;
        *(short8*)(outp + base + (size_t)d*1024 + seg*8) =
            *(const short8*)&Cs[nloc*136 + seg*8];
      }
    }
  }
}

// ---------------- fused attention (unchanged from R14) ----------------
__global__ __launch_bounds__(512, 4) void k_attn(
    const u16* __restrict__ qws, const u16* __restrict__ kws, const u16* __restrict__ vtws,
    const u16* __restrict__ relk80, const u16* __restrict__ relvT,
    const float* __restrict__ tree_emb, const u32* __restrict__ packed,
    u16* __restrict__ ctx) {
  __shared__ u16 Kb[2][2048];       // [buf][32 k-rows][64 d] swizzled
  __shared__ u16 Vb[2][2048];       // [buf][64 d-rows][32 k] swizzled
  __shared__ u16 qdotL[8*16*68];    // [w][q][bucket]  (band tiles)
  __shared__ u16 PB[8][16*96];      // per-wave banded P
  __shared__ u16 Pl[8][16*40];      // per-wave C->A bridge, stride 40

  int tid = threadIdx.x, lane = tid & 63, wv = tid >> 6;
  int quad = lane >> 4, l15 = lane & 15;
  int qb = blockIdx.x, h = blockIdx.y, b = blockIdx.z;
  int q0 = qb * 128 + wv * 16;

  // register tree table: lane v (0..63) holds tree_emb[v][h] * log2e
  float treev = tree_emb[lane * 8 + h] * 1.44269504f;

  #pragma unroll
  for (int i = 0; i < 12; i++) ((u32*)&PB[wv][0])[lane + i*64] = 0u;

  const u16* qp = qws  + (size_t)(b*8 + h)*(1024*64);
  const u16* kp = kws  + (size_t)(b*8 + h)*(1024*64);
  const u16* vp = vtws + (size_t)(b*8 + h)*(64*1024);
  const u32* pkb = packed + ((size_t)b << 20);

  // staging roles: waves 0-3 carry K rows; waves 4-7 carry V rows.
  int rk = (wv & 3)*8 + (lane >> 3);
  int swk = (((lane & 7)*8) ^ ((rk & 7) << 3));
  int rv = (wv & 3)*16 + (lane >> 2);
  const u16* vsrc = vp + (size_t)rv*1024 + (((lane & 3)*8) ^ ((rv & 3) << 3));

#define STAGE(kt, nb) do { \
    if (wv < 4) GLDS16(kp + (size_t)((kt)*32 + rk)*64 + swk, &Kb[nb][wv*512]); \
    else        GLDS16(vsrc + (kt)*32, &Vb[nb][(wv & 3)*512]); \
  } while (0)

  STAGE(0, 0);

  short8 aQ[2];
  #pragma unroll
  for (int kf = 0; kf < 2; kf++)
    aQ[kf] = *(const short8*)(qp + (q0 + l15)*64 + kf*32 + quad*8);

  float qd0[4], qd64[4];
  #pragma unroll
  for (int t = 0; t < 5; t++) {
    f32x4 C = (f32x4){0.f,0.f,0.f,0.f};
    #pragma unroll
    for (int kf = 0; kf < 2; kf++) {
      short8 bR = *(const short8*)(relk80 + (t*16 + l15)*64 + kf*32 + quad*8);
      C = __builtin_amdgcn_mfma_f32_16x16x32_bf16(aQ[kf], bR, C, 0, 0, 0);
    }
    if (t == 0) {
      #pragma unroll
      for (int r = 0; r < 4; r++) qd0[r] = __shfl(C[r], lane & 48, 64);
    }
    if (t == 4) {
      #pragma unroll
      for (int r = 0; r < 4; r++) qd64[r] = __shfl(C[r], lane & 48, 64);
    }
    int col = t*16 + l15;
    if (col < 65) {
      #pragma unroll
      for (int r = 0; r < 4; r++)
        qdotL[(wv*16 + quad*4 + r)*68 + col] = f2bf(C[r]);
    }
  }

  int t_lo = max(0, (q0 - 31) >> 5);
  int t_hi = min(31, (q0 + 46) >> 5);

  // precomputed LDS read offsets (u16 units); ct adds 1024, t adds 512
  int sK = (l15 & 7) << 3;
  int kbo0 = l15*64 + ((quad*8) ^ sK);          // kf=0
  int kbo1 = l15*64 + (((4 + quad)*8) ^ sK);    // kf=1
  int vbo  = l15*32 + ((quad*8) ^ ((l15 & 3) << 3));

  u32 pk[8];
  #pragma unroll
  for (int e = 0; e < 8; e++)
    pk[e] = pkb[((q0 + quad*4 + (e & 3)) << 10) + (e >> 2)*16 + l15];

  f32x4 O[4];
  float rs[4], ts0[4], ts1[4];
  #pragma unroll
  for (int t = 0; t < 4; t++) O[t] = (f32x4){0.f,0.f,0.f,0.f};
  #pragma unroll
  for (int r = 0; r < 4; r++) { rs[r] = 0.f; ts0[r] = 0.f; ts1[r] = 0.f; }

  for (int jt = 0; jt < 32; ++jt) {
    int cur = jt & 1;
    int k0 = jt << 5;
    __syncthreads();                    // stage(jt) complete; readers of buf cur^1 done
    if (jt < 31) STAGE(jt + 1, cur ^ 1);

    u32 pkc[8];
    #pragma unroll
    for (int e = 0; e < 8; e++) pkc[e] = pk[e];
    if (jt < 31) {
      int kn = (jt + 1) << 5;
      #pragma unroll
      for (int e = 0; e < 8; e++)
        pk[e] = pkb[((q0 + quad*4 + (e & 3)) << 10) + kn + (e >> 2)*16 + l15];
    }

    short8 kr00 = *(const short8*)&Kb[cur][kbo0];
    short8 kr01 = *(const short8*)&Kb[cur][kbo1];
    short8 kr10 = *(const short8*)&Kb[cur][1024 + kbo0];
    short8 kr11 = *(const short8*)&Kb[cur][1024 + kbo1];
    short8 vr[4];
    #pragma unroll
    for (int t = 0; t < 4; t++) vr[t] = *(const short8*)&Vb[cur][t*512 + vbo];

    f32x4 S0 = (f32x4){0.f,0.f,0.f,0.f}, S1 = (f32x4){0.f,0.f,0.f,0.f};
    __builtin_amdgcn_s_setprio(1);
    S0 = __builtin_amdgcn_mfma_f32_16x16x32_bf16(aQ[0], kr00, S0, 0, 0, 0);
    S0 = __builtin_amdgcn_mfma_f32_16x16x32_bf16(aQ[1], kr01, S0, 0, 0, 0);
    S1 = __builtin_amdgcn_mfma_f32_16x16x32_bf16(aQ[0], kr10, S1, 0, 0, 0);
    S1 = __builtin_amdgcn_mfma_f32_16x16x32_bf16(aQ[1], kr11, S1, 0, 0, 0);
    __builtin_amdgcn_s_setprio(0);
    f32x4 Scur[2] = { S0, S1 };

    if (jt < t_lo) {
      #pragma unroll
      for (int ct = 0; ct < 2; ct++) {
        float pv[4];
        #pragma unroll
        for (int r = 0; r < 4; r++) {
          u32 sg = pkc[ct*4 + r];
          float rw = __uint_as_float(sg & 0xffff0000u);
          float tb = __int_as_float(__builtin_amdgcn_ds_bpermute(
              (int)((sg & 63u) << 2), __float_as_int(treev)));
          float qm = (sg & 128u) ? -1e30f : qd0[r];
          float p = fexp2(__builtin_fmaf(tb, rw, Scur[ct][r] + qm));
          ts0[r] += p;
          pv[r] = p;
        }
        u32 c01 = cvtpk(pv[0], pv[1]), c23 = cvtpk(pv[2], pv[3]);
        u16* pl = &Pl[wv][(quad*4)*40 + ct*16 + l15];
        pl[0]   = (u16)c01; pl[40]  = (u16)(c01 >> 16);
        pl[80]  = (u16)c23; pl[120] = (u16)(c23 >> 16);
      }
    } else if (jt > t_hi) {
      #pragma unroll
      for (int ct = 0; ct < 2; ct++) {
        float pv[4];
        #pragma unroll
        for (int r = 0; r < 4; r++) {
          u32 sg = pkc[ct*4 + r];
          float rw = __uint_as_float(sg & 0xffff0000u);
          float tb = __int_as_float(__builtin_amdgcn_ds_bpermute(
              (int)((sg & 63u) << 2), __float_as_int(treev)));
          float qm = (sg & 128u) ? -1e30f : qd64[r];
          float p = fexp2(__builtin_fmaf(tb, rw, Scur[ct][r] + qm));
          ts1[r] += p;
          pv[r] = p;
        }
        u32 c01 = cvtpk(pv[0], pv[1]), c23 = cvtpk(pv[2], pv[3]);
        u16* pl = &Pl[wv][(quad*4)*40 + ct*16 + l15];
        pl[0]   = (u16)c01; pl[40]  = (u16)(c01 >> 16);
        pl[80]  = (u16)c23; pl[120] = (u16)(c23 >> 16);
      }
    } else {
      #pragma unroll
      for (int ct = 0; ct < 2; ct++) {
        float pv[4];
        #pragma unroll
        for (int r = 0; r < 4; r++) {
          int kloc = ct*16 + l15, qloc = quad*4 + r;
          int d = (k0 + kloc) - (q0 + qloc);
          int bucket = min(max(d + 32, 0), 64);
          u32 sg = pkc[ct*4 + r];
          float rw = __uint_as_float(sg & 0xffff0000u);
          float tb = __int_as_float(__builtin_amdgcn_ds_bpermute(
              (int)((sg & 63u) << 2), __float_as_int(treev)));
          float qd = bf2f(qdotL[(wv*16 + qloc)*68 + bucket]);
          float qm = (sg & 128u) ? -1e30f : qd;
          float p = fexp2(__builtin_fmaf(tb, rw, Scur[ct][r] + qm));
          if (d <= -32)      ts0[r] += p;
          else if (d >= 32)  ts1[r] += p;
          else             { rs[r] += p; PB[wv][qloc*96 + d + 32] = f2bf(p); }
          pv[r] = p;
        }
        u32 c01 = cvtpk(pv[0], pv[1]), c23 = cvtpk(pv[2], pv[3]);
        u16* pl = &Pl[wv][(quad*4)*40 + ct*16 + l15];
        pl[0]   = (u16)c01; pl[40]  = (u16)(c01 >> 16);
        pl[80]  = (u16)c23; pl[120] = (u16)(c23 >> 16);
      }
    }

    {
      short8 aP = *(const short8*)&Pl[wv][l15*40 + quad*8];
      __builtin_amdgcn_s_setprio(1);
      #pragma unroll
      for (int t = 0; t < 4; t++)
        O[t] = __builtin_amdgcn_mfma_f32_16x16x32_bf16(aP, vr[t], O[t], 0, 0, 0);
      __builtin_amdgcn_s_setprio(0);
    }
  }
#undef STAGE

  #pragma unroll
  for (int m = 1; m < 16; m <<= 1) {
    #pragma unroll
    for (int r = 0; r < 4; r++) {
      rs[r]  += __shfl_xor(rs[r],  m, 64);
      ts0[r] += __shfl_xor(ts0[r], m, 64);
      ts1[r] += __shfl_xor(ts1[r], m, 64);
    }
  }
  if (l15 == 0) {
    #pragma unroll
    for (int r = 0; r < 4; r++) {
      PB[wv][(quad*4 + r)*96 + 0]  = f2bf(ts0[r]);
      PB[wv][(quad*4 + r)*96 + 64] = f2bf(ts1[r]);
    }
  }
  // PB is per-wave: ds_write -> ds_read within the same wave, no barrier.

  {
    short8 aB[3];
    #pragma unroll
    for (int s = 0; s < 3; s++)
      aB[s] = *(const short8*)&PB[wv][l15*96 + s*32 + quad*8];
    #pragma unroll
    for (int t = 0; t < 4; t++)
      #pragma unroll
      for (int s = 0; s < 3; s++) {
        short8 bRV = *(const short8*)(relvT + (t*16 + l15)*96 + s*32 + quad*8);
        O[t] = __builtin_amdgcn_mfma_f32_16x16x32_bf16(aB[s], bRV, O[t], 0, 0, 0);
      }
  }

  {
    float inv[4];
    #pragma unroll
    for (int r = 0; r < 4; r++) inv[r] = 1.0f / (rs[r] + ts0[r] + ts1[r]);
    #pragma unroll
    for (int t = 0; t < 4; t++)
      #pragma unroll
      for (int r = 0; r < 4; r++) {
        int qg = q0 + quad*4 + r;
        ctx[(b*1024 + qg)*512 + h*64 + t*16 + l15] = f2bf(O[t][r] * inv[r]);
      }
  }
}

extern "C" void kernel_launch(void* const* d_in, const int* in_sizes, int n_in,
                              void* d_out, int out_size, void* d_ws, size_t ws_size,
                              hipStream_t stream) {
  const float* key   = (const float*)d_in[0];
  const float* value = (const float*)d_in[1];
  const float* query = (const float*)d_in[2];
  const unsigned char* maskp = (const unsigned char*)d_in[3];
  const int*   relm  = (const int*)d_in[4];
  const float* relw  = (const float*)d_in[5];
  const float* Wk = (const float*)d_in[6];
  const float* bk = (const float*)d_in[7];
  const float* Wq = (const float*)d_in[8];
  const float* bq = (const float*)d_in[9];
  const float* Wv = (const float*)d_in[10];
  const float* bv = (const float*)d_in[11];
  const float* Wo = (const float*)d_in[12];
  const float* bo = (const float*)d_in[13];
  const float* rek = (const float*)d_in[14];
  const float* rev = (const float*)d_in[15];
  const float* te  = (const float*)d_in[16];
  (void)in_sizes; (void)n_in; (void)out_size;

  char* w = (char*)d_ws;
  size_t off = 0;
  auto alloc = [&](size_t bytes) -> void* {
    void* p = w + off; off += (bytes + 255) & ~(size_t)255; return p;
  };
  u16* WkT = (u16*)alloc((size_t)512*512*2);
  u16* WqT = (u16*)alloc((size_t)512*512*2);
  u16* WvT = (u16*)alloc((size_t)512*512*2);
  u16* WoT = (u16*)alloc((size_t)512*512*2);
  u16* qws = (u16*)alloc((size_t)8*8*1024*64*2);   // [B,H,L,64], pre-scaled 0.125*log2e
  u16* kws = (u16*)alloc((size_t)8*8*1024*64*2);   // [B,H,L,64]
  u16* vt  = (u16*)alloc((size_t)8*8*1024*64*2);   // [B,H,64,L]
  u32* packed = (u32*)alloc((size_t)8*1024*1024*4);
  u16* ctxb = (u16*)alloc((size_t)8192*512*2);     // [B,L,512] bf16
  u16* relk80 = (u16*)alloc((size_t)80*64*2);
  u16* relvT  = (u16*)alloc((size_t)64*96*2);
  if (off > ws_size) return;

  k_pre<<<1068, 256, 0, stream>>>(Wk, Wq, Wv, Wo, WkT, WqT, WvT, WoT,
                                  rek, rev, relk80, relvT);

  // Q pre-scaled by 0.125 * log2(e): softmax computed in exp2 domain.
  FArg aq { query, WqT, bq, (void*)qws, 1, 0.18033688f };
  FArg ak { key,   WkT, bk, (void*)kws, 1, 1.0f };
  FArg av { value, WvT, bv, (void*)vt,  2, 1.0f };
  k_gemmf<<<8960, 256, 0, stream>>>(aq, ak, av, relm, relw, maskp, packed);

  k_attn<<<dim3(8,8,8), 512, 0, stream>>>(qws, kws, vt, relk80, relvT, te, packed, ctxb);

  GArg ao { ctxb, WoT, bo, d_out, 0, 1.0f };
  k_gemm<<<dim3(4,64,1), 256, 0, stream>>>(ao, ao, ao);
}